// Round 8
// baseline (453.472 us; speedup 1.0000x reference)
//
#include <hip/hip_runtime.h>
#include <hip/hip_bf16.h>

using bf16 = __hip_bfloat16;
typedef __attribute__((ext_vector_type(8))) short bf16x8;
typedef __attribute__((ext_vector_type(4))) float f32x4;

#define DM 2048

// ---- workspace offsets (bytes) ----
#define OFF_WCZQ  0x00000000ULL  // 768x2048 bf16 (w_kv^T | w_z^T | w_dq^T)
#define OFF_WUQ   0x00300000ULL  // 2048x512 bf16
#define OFF_DOWNB 0x00500000ULL  // 4x512x512 bf16 (o_down, plain cvt)
#define OFF_WUP   0x00700000ULL  // 2048x2048 bf16 (o_up^T)
#define OFF_W2T   0x00F00000ULL  // 2048x2048 bf16 (fused down*up, transposed)
#define OFF_KC    0x01700000ULL  // 2*64*128 bf16
#define OFF_VT    0x01710000ULL  // 2*128*64 bf16 (V transposed per batch)
#define OFF_ROPE  0x01720000ULL  // 8192*32 float2
#define OFF_XB    0x01A00000ULL  // 16384x2048 bf16 (x), reused for attn-out
#define OFF_CZQ   0x05A00000ULL  // 16384x768 bf16 (c_proj | z | q_mid)
#define OFF_QF    0x07300000ULL  // 16384x2048 bf16

__device__ __forceinline__ void async16(const void* g, void* l) {
  __builtin_amdgcn_global_load_lds(
      (const __attribute__((address_space(1))) unsigned int*)g,
      (__attribute__((address_space(3))) unsigned int*)l, 16, 0, 0);
}

__device__ __forceinline__ f32x4 mfma16(bf16x8 a, bf16x8 b, f32x4 c) {
  return __builtin_amdgcn_mfma_f32_16x16x32_bf16(a, b, c, 0, 0, 0);
}

__device__ __forceinline__ float b2f(short u) {
  unsigned x = ((unsigned)(unsigned short)u) << 16;
  return __builtin_bit_cast(float, x);
}
__device__ __forceinline__ short f2bs(float f) {
  return __builtin_bit_cast(short, __float2bfloat16(f));
}

#define SB0 __builtin_amdgcn_sched_barrier(0)

// ---------------- weight transpose: src (K x N) f32 -> dst (N x K) bf16 ----------------
__global__ __launch_bounds__(256) void transpose_f32_bf16(
    const float* __restrict__ src, bf16* __restrict__ dst, int K, int N) {
  __shared__ float t[32][33];
  const int tn0 = blockIdx.x * 32, tk0 = blockIdx.y * 32;
  const int lx = threadIdx.x & 31, ly = threadIdx.x >> 5;
#pragma unroll
  for (int p = 0; p < 4; p++) {
    int k = tk0 + ly + p * 8, n = tn0 + lx;
    if (k < K && n < N) t[ly + p * 8][lx] = src[(size_t)k * N + n];
  }
  __syncthreads();
#pragma unroll
  for (int p = 0; p < 4; p++) {
    int n = tn0 + ly + p * 8, k = tk0 + lx;
    if (n < N && k < K) dst[(size_t)n * K + k] = __float2bfloat16(t[lx][ly + p * 8]);
  }
}

// ---------------- f32 -> bf16 bulk convert ----------------
__global__ __launch_bounds__(256) void cvt_bf16_k(const float* __restrict__ in, bf16* __restrict__ out) {
  size_t i = ((size_t)blockIdx.x * 256 + threadIdx.x) * 8;
  float4 a = *(const float4*)(in + i);
  float4 b = *(const float4*)(in + i + 4);
  struct alignas(16) B8 { bf16 v[8]; } r;
  r.v[0] = __float2bfloat16(a.x); r.v[1] = __float2bfloat16(a.y);
  r.v[2] = __float2bfloat16(a.z); r.v[3] = __float2bfloat16(a.w);
  r.v[4] = __float2bfloat16(b.x); r.v[5] = __float2bfloat16(b.y);
  r.v[6] = __float2bfloat16(b.z); r.v[7] = __float2bfloat16(b.w);
  *(B8*)(out + i) = r;
}

// ---------------- rope cos/sin table [8192][32] ----------------
__global__ __launch_bounds__(256) void rope_table_k(float2* __restrict__ tab) {
  int idx = blockIdx.x * 256 + threadIdx.x;
  int s = idx >> 5, i = idx & 31;
  double f = pow(10000.0, -((double)(2 * i)) / 64.0);
  double a = (double)s * f;
  tab[idx] = make_float2((float)cos(a), (float)sin(a));
}

// ================= 256x256 8-phase GEMM: C = A(MxK,lda) @ Bt(NxK,ldb)^T =================
// 512 thr / 8 waves (2Mx4N); BK=64 as 2 k-halves; LDS [2dbuf][A,B][2kh][256][32] = 128 KiB.
// Counted vmcnt(4) at 2 sync points per K-tile; max 8 outstanding global_load_lds/wave.
// STABLE STRUCTURE — deeper pipelines (12 outstanding) were replay-nondeterministic; do not deepen.
template <int OUT_BF16>
__global__ __launch_bounds__(512, 2) void gemm8p(
    const bf16* __restrict__ A, int lda,
    const bf16* __restrict__ Bt, int ldb,
    void* __restrict__ Cp, int ldc, int K, int ntiles) {
  __shared__ bf16 lds[2][2][2][256][32];  // 131072 B
  const int tid = threadIdx.x;
  const int lane = tid & 63, wid = tid >> 6;
  const int wr = wid >> 2, wc = wid & 3;
  const int wgid = (blockIdx.x & 7) * (gridDim.x >> 3) + (blockIdx.x >> 3);
  const int mt = wgid / ntiles, nt = wgid % ntiles;
  const int srow = tid >> 2, sunit = tid & 3;
  const bf16* gA = A + (size_t)(mt * 256 + srow) * lda + (sunit << 3);
  const bf16* gB = Bt + (size_t)(nt * 256 + srow) * ldb + (sunit << 3);
  char* ldsA = (char*)lds + tid * 16;
  char* ldsB = (char*)lds + 32768 + tid * 16;

#define STAGE_A(dd, h, kc) do { \
    const bf16* _s = gA + (kc) + (h) * 32; \
    char* _d = ldsA + (dd) * 65536 + (h) * 16384; \
    async16(_s, _d); \
    async16(_s + (size_t)128 * lda, _d + 8192); } while (0)
#define STAGE_B(dd, h, kc) do { \
    const bf16* _s = gB + (kc) + (h) * 32; \
    char* _d = ldsB + (dd) * 65536 + (h) * 16384; \
    async16(_s, _d); \
    async16(_s + (size_t)128 * ldb, _d + 8192); } while (0)

  const int l15 = lane & 15, g = lane >> 4;
  const char* ardb = (char*)lds + (size_t)(wr * 128 + l15) * 64 + (g << 4);
  const char* brdb = (char*)lds + 32768 + (size_t)(wc * 64 + l15) * 64 + (g << 4);

  f32x4 acc[8][4] = {};
  // prologue: stage K-tile 0 (FIFO: A-h0, B-h0, A-h1, B-h1 = 8 loads)
  STAGE_A(0, 0, 0); STAGE_B(0, 0, 0); STAGE_A(0, 1, 0); STAGE_B(0, 1, 0);

  const int nkt = K >> 6;
  for (int t = 0; t < nkt; ++t) {
    const int d = t & 1;
    const char* aB = ardb + d * 65536;
    const char* bB = brdb + d * 65536;
    const int kn = (t + 1) << 6;
    const bool pf = (t + 1) < nkt;
    bf16x8 a[8], b0, b1;
    // ---- P1: sync (A-h0,B-h0 landed), stage A-h0', compute (h0, n0/n1) ----
    SB0;
    asm volatile("s_waitcnt vmcnt(4)" ::: "memory");
    __builtin_amdgcn_s_barrier();
    asm volatile("" ::: "memory");
    SB0;
    if (pf) STAGE_A(d ^ 1, 0, kn);
#pragma unroll
    for (int m = 0; m < 8; m++) a[m] = *(const bf16x8*)(aB + m * 1024);
    b0 = *(const bf16x8*)(bB);
    b1 = *(const bf16x8*)(bB + 1024);
    __builtin_amdgcn_s_setprio(1);
#pragma unroll
    for (int m = 0; m < 8; m++) {
      acc[m][0] = mfma16(a[m], b0, acc[m][0]);
      acc[m][1] = mfma16(a[m], b1, acc[m][1]);
    }
    __builtin_amdgcn_s_setprio(0);
    // ---- P2: stage B-h0', compute (h0, n2/n3) ----
    if (pf) STAGE_B(d ^ 1, 0, kn);
    b0 = *(const bf16x8*)(bB + 2048);
    b1 = *(const bf16x8*)(bB + 3072);
    __builtin_amdgcn_s_setprio(1);
#pragma unroll
    for (int m = 0; m < 8; m++) {
      acc[m][2] = mfma16(a[m], b0, acc[m][2]);
      acc[m][3] = mfma16(a[m], b1, acc[m][3]);
    }
    __builtin_amdgcn_s_setprio(0);
    // ---- P3: sync (A-h1,B-h1 landed), stage A-h1', compute (h1, n0/n1) ----
    SB0;
    if (pf) asm volatile("s_waitcnt vmcnt(4)" ::: "memory");
    else    asm volatile("s_waitcnt vmcnt(0)" ::: "memory");
    __builtin_amdgcn_s_barrier();
    asm volatile("" ::: "memory");
    SB0;
    if (pf) STAGE_A(d ^ 1, 1, kn);
#pragma unroll
    for (int m = 0; m < 8; m++) a[m] = *(const bf16x8*)(aB + 16384 + m * 1024);
    b0 = *(const bf16x8*)(bB + 16384);
    b1 = *(const bf16x8*)(bB + 16384 + 1024);
    __builtin_amdgcn_s_setprio(1);
#pragma unroll
    for (int m = 0; m < 8; m++) {
      acc[m][0] = mfma16(a[m], b0, acc[m][0]);
      acc[m][1] = mfma16(a[m], b1, acc[m][1]);
    }
    __builtin_amdgcn_s_setprio(0);
    // ---- P4: stage B-h1', compute (h1, n2/n3) ----
    if (pf) STAGE_B(d ^ 1, 1, kn);
    b0 = *(const bf16x8*)(bB + 16384 + 2048);
    b1 = *(const bf16x8*)(bB + 16384 + 3072);
    __builtin_amdgcn_s_setprio(1);
#pragma unroll
    for (int m = 0; m < 8; m++) {
      acc[m][2] = mfma16(a[m], b0, acc[m][2]);
      acc[m][3] = mfma16(a[m], b1, acc[m][3]);
    }
    __builtin_amdgcn_s_setprio(0);
  }
#undef STAGE_A
#undef STAGE_B

  const int r4 = (lane >> 4) << 2;
  const size_t row0 = (size_t)mt * 256 + wr * 128;
  const int col0 = nt * 256 + wc * 64;
#pragma unroll
  for (int m = 0; m < 8; m++)
#pragma unroll
    for (int n = 0; n < 4; n++)
#pragma unroll
      for (int j = 0; j < 4; j++) {
        size_t row = row0 + m * 16 + r4 + j;
        size_t col = (size_t)col0 + n * 16 + l15;
        if (OUT_BF16) ((bf16*)Cp)[row * ldc + col] = __float2bfloat16(acc[m][n][j]);
        else          ((float*)Cp)[row * ldc + col] = acc[m][n][j];
      }
}

// ---------------- generic bf16 GEMM (128² m97-style) — small W2T prep ----------------
template <int OUT_BF16>
__global__ __launch_bounds__(256) void gemm_bt(
    const bf16* __restrict__ A, int lda,
    const bf16* __restrict__ Bt, int ldb,
    void* __restrict__ Cp, int ldc, int K, int ntiles) {
  __shared__ bf16 As[128 * 32];
  __shared__ bf16 Bs[128 * 32];
  const int tid = threadIdx.x;
  const int wave = tid >> 6, lane = tid & 63;
  const int wgid = (blockIdx.x & 7) * (gridDim.x >> 3) + (blockIdx.x >> 3);
  const int mt = wgid / ntiles, nt = wgid % ntiles;
  const int srow = tid >> 2, scol = (tid & 3) << 3;
  const bf16* ag = A + (size_t)(mt * 128 + srow) * lda + scol;
  const bf16* bg = Bt + (size_t)(nt * 128 + srow) * ldb + scol;
  char* asw = (char*)As + wave * 1024;
  char* bsw = (char*)Bs + wave * 1024;
  const int l15 = lane & 15, lk = (lane >> 4) << 3;
  const int wm = (wave >> 1) * 64, wn = (wave & 1) * 64;
  f32x4 acc[4][4] = {};
  for (int kt = 0; kt < K; kt += 32) {
    __syncthreads();
    async16(ag + kt, asw);
    async16(ag + kt + (size_t)64 * lda, asw + 4096);
    async16(bg + kt, bsw);
    async16(bg + kt + (size_t)64 * ldb, bsw + 4096);
    __syncthreads();
    bf16x8 af[4], bfr[4];
#pragma unroll
    for (int m = 0; m < 4; m++)
      af[m] = *(const bf16x8*)((const char*)As + (size_t)((wm + m * 16 + l15) * 32 + lk) * 2);
#pragma unroll
    for (int n = 0; n < 4; n++)
      bfr[n] = *(const bf16x8*)((const char*)Bs + (size_t)((wn + n * 16 + l15) * 32 + lk) * 2);
#pragma unroll
    for (int m = 0; m < 4; m++)
#pragma unroll
      for (int n = 0; n < 4; n++)
        acc[m][n] = mfma16(af[m], bfr[n], acc[m][n]);
  }
  const int r4 = (lane >> 4) << 2;
#pragma unroll
  for (int m = 0; m < 4; m++)
#pragma unroll
    for (int n = 0; n < 4; n++)
#pragma unroll
      for (int j = 0; j < 4; j++) {
        size_t row = (size_t)mt * 128 + wm + m * 16 + r4 + j;
        size_t col = (size_t)nt * 128 + wn + n * 16 + l15;
        if (OUT_BF16) ((bf16*)Cp)[row * ldc + col] = __float2bfloat16(acc[m][n][j]);
        else          ((float*)Cp)[row * ldc + col] = acc[m][n][j];
      }
}

// ---------------- compression: softmax over M + weighted sum, LN; writes K and V^T ----------------
__global__ __launch_bounds__(512) void compress_k(
    const bf16* __restrict__ cz, int ldcz, const float* __restrict__ b_comp,
    const float* __restrict__ gamma, const float* __restrict__ beta,
    bf16* __restrict__ k_comp, bf16* __restrict__ vt) {
  const int blk = blockIdx.x;
  const int t = threadIdx.x, c = t & 127, qtr = t >> 7;
  const size_t t0 = (size_t)blk * 128;
  float num = 0.f, den = 0.f;
  for (int m = qtr * 32; m < qtr * 32 + 32; m++) {
    const bf16* r = cz + (t0 + m) * ldcz;
    float w = expf(__bfloat162float(r[128 + c]) + b_comp[m * 128 + c]);
    den += w;
    num += w * __bfloat162float(r[c]);
  }
  __shared__ float sn[4][128], sd[4][128], sv[128];
  sn[qtr][c] = num;
  sd[qtr][c] = den;
  __syncthreads();
  if (qtr == 0)
    sv[c] = (sn[0][c] + sn[1][c] + sn[2][c] + sn[3][c]) /
            (sd[0][c] + sd[1][c] + sd[2][c] + sd[3][c]);
  __syncthreads();
  if (qtr == 0) {
    float v = sv[c];
    float mu = 0.f;
    for (int i = 0; i < 128; i++) mu += sv[i];
    mu *= (1.f / 128.f);
    float var = 0.f;
    for (int i = 0; i < 128; i++) { float d = sv[i] - mu; var += d * d; }
    var *= (1.f / 128.f);
    float kc = (v - mu) * rsqrtf(var + 1e-6f) * gamma[c] + beta[c];
    const int b = blk >> 6, kb = blk & 63;
    k_comp[(size_t)blk * 128 + c] = __float2bfloat16(kc);
    vt[(size_t)b * 8192 + c * 64 + kb] = __float2bfloat16(v);
  }
}

// ---------------- attention: fused q-LN+RoPE, K/V^T direct from global, swizzled LDS ----------------
__global__ __launch_bounds__(256) void attn_k(
    const bf16* __restrict__ qln, const bf16* __restrict__ kc,
    const bf16* __restrict__ vt, const float* __restrict__ sink_logits,
    const float* __restrict__ gamma, const float* __restrict__ beta,
    const float2* __restrict__ rope, bf16* __restrict__ out) {
  __shared__ bf16 Qs[128 * 128];  // swizzled rows; P[128][64] overlays after QK^T
  const int qt = blockIdx.x, hh = blockIdx.y, b = blockIdx.z;
  const int nk = qt + 1;
  const int ntk = (nk + 15) >> 4;
  const int nkk = (nk + 31) >> 5;
  const int tid = threadIdx.x, wave = tid >> 6, lane = tid & 63;
  const int l15 = lane & 15, g = lane >> 4;
  const size_t t0 = (size_t)b * 8192 + (size_t)qt * 128;
  const bf16* kbase = kc + (size_t)b * 64 * 128;
  const bf16* vbase = vt + (size_t)b * 128 * 64;

  {
    const int q = tid >> 1, hf = tid & 1;
    const bf16* gq = qln + (t0 + q) * 2048 + hh * 128 + hf * 64;
    bf16x8 r[8];
#pragma unroll
    for (int i = 0; i < 8; i++) r[i] = *(const bf16x8*)(gq + i * 8);
    float sum = 0.f;
#pragma unroll
    for (int i = 0; i < 8; i++)
#pragma unroll
      for (int j = 0; j < 8; j++) sum += b2f(r[i][j]);
    sum += __shfl_xor(sum, 1);
    const float mu = sum * (1.f / 128.f);
    float var = 0.f;
#pragma unroll
    for (int i = 0; i < 8; i++)
#pragma unroll
      for (int j = 0; j < 8; j++) { float d = b2f(r[i][j]) - mu; var += d * d; }
    var += __shfl_xor(var, 1);
    const float inv = rsqrtf(var * (1.f / 128.f) + 1e-6f);
    const int c0 = hf * 64;
#pragma unroll
    for (int i = 0; i < 8; i++) {
      float y[8];
#pragma unroll
      for (int j = 0; j < 8; j++) {
        int ch = c0 + i * 8 + j;
        y[j] = (b2f(r[i][j]) - mu) * inv * gamma[ch] + beta[ch];
      }
      if (hf) {
#pragma unroll
        for (int j = 0; j < 8; j += 2) {
          float2 cs = rope[((size_t)qt * 128 + q) * 32 + i * 4 + (j >> 1)];
          float e = y[j], o = y[j + 1];
          y[j] = e * cs.x - o * cs.y;
          y[j + 1] = e * cs.y + o * cs.x;
        }
      }
      bf16x8 w;
#pragma unroll
      for (int j = 0; j < 8; j++) w[j] = f2bs(y[j]);
      *(bf16x8*)(Qs + q * 128 + ((hf * 8 + (i ^ (q & 7))) << 3)) = w;
    }
  }
  __syncthreads();

  bf16x8 af[2][4];
#pragma unroll
  for (int m = 0; m < 2; m++) {
    const int q = wave * 32 + m * 16 + l15;
#pragma unroll
    for (int kk = 0; kk < 4; kk++) {
      const int u = (kk * 4 + g) ^ (q & 7);
      af[m][kk] = *(const bf16x8*)(Qs + q * 128 + u * 8);
    }
  }
  __syncthreads();  // Qs dead; safe to overlay P

  f32x4 sacc[2][4] = {};
#pragma unroll
  for (int n = 0; n < 4; n++) {
    if (n < ntk) {
      const bf16* kr = kbase + (n * 16 + l15) * 128 + g * 8;
      bf16x8 b0 = *(const bf16x8*)(kr);
      bf16x8 b1 = *(const bf16x8*)(kr + 32);
      bf16x8 b2 = *(const bf16x8*)(kr + 64);
      bf16x8 b3 = *(const bf16x8*)(kr + 96);
      __builtin_amdgcn_s_setprio(1);
      sacc[0][n] = mfma16(af[0][0], b0, sacc[0][n]);
      sacc[1][n] = mfma16(af[1][0], b0, sacc[1][n]);
      sacc[0][n] = mfma16(af[0][1], b1, sacc[0][n]);
      sacc[1][n] = mfma16(af[1][1], b1, sacc[1][n]);
      sacc[0][n] = mfma16(af[0][2], b2, sacc[0][n]);
      sacc[1][n] = mfma16(af[1][2], b2, sacc[1][n]);
      sacc[0][n] = mfma16(af[0][3], b3, sacc[0][n]);
      sacc[1][n] = mfma16(af[1][3], b3, sacc[1][n]);
      __builtin_amdgcn_s_setprio(0);
    }
  }

  const float sink = expf(sink_logits[hh]);
  const float scale = 0.088388347648318447f;  // 1/sqrt(128)
  bf16* P = Qs;
#pragma unroll
  for (int m = 0; m < 2; m++) {
    float pv[4][4];
    float rs[4] = {0.f, 0.f, 0.f, 0.f};
#pragma unroll
    for (int n = 0; n < 4; n++) {
      int key = n * 16 + l15;
#pragma unroll
      for (int j = 0; j < 4; j++) {
        float p = (key < nk) ? expf(sacc[m][n][j] * scale) : 0.f;
        pv[n][j] = p;
        rs[j] += p;
      }
    }
#pragma unroll
    for (int j = 0; j < 4; j++) {
      float v = rs[j];
      v += __shfl_xor(v, 1); v += __shfl_xor(v, 2);
      v += __shfl_xor(v, 4); v += __shfl_xor(v, 8);
      rs[j] = 1.0f / (v + sink);
    }
    const int row0 = wave * 32 + m * 16 + (g << 2);
#pragma unroll
    for (int n = 0; n < 4; n++)
#pragma unroll
      for (int j = 0; j < 4; j++) {
        int q = row0 + j;
        int k = n * 16 + l15;
        P[q * 64 + ((((k >> 3) ^ (q & 7)) << 3) | (k & 7))] =
            __float2bfloat16(pv[n][j] * rs[j]);
      }
  }
  // no barrier: PV reads only this wave's own P rows

  f32x4 oacc[2][8] = {};
#pragma unroll
  for (int kk = 0; kk < 2; kk++) {
    if (kk < nkk) {
      bf16x8 pa[2];
#pragma unroll
      for (int m = 0; m < 2; m++) {
        const int q = wave * 32 + m * 16 + l15;
        const int u = (kk * 4 + g) ^ (q & 7);
        pa[m] = *(const bf16x8*)(P + q * 64 + u * 8);
      }
#pragma unroll
      for (int n = 0; n < 8; n++) {
        bf16x8 vb = *(const bf16x8*)(vbase + (n * 16 + l15) * 64 + kk * 32 + g * 8);
        __builtin_amdgcn_s_setprio(1);
        oacc[0][n] = mfma16(pa[0], vb, oacc[0][n]);
        oacc[1][n] = mfma16(pa[1], vb, oacc[1][n]);
        __builtin_amdgcn_s_setprio(0);
      }
    }
  }

  bf16* ob = out + t0 * 2048 + hh * 128;
  const int r4 = g << 2;
#pragma unroll
  for (int m = 0; m < 2; m++)
#pragma unroll
    for (int n = 0; n < 8; n++)
#pragma unroll
      for (int j = 0; j < 4; j++)
        ob[(size_t)(wave * 32 + m * 16 + r4 + j) * 2048 + n * 16 + l15] =
            __float2bfloat16(oacc[m][n][j]);
}

extern "C" void kernel_launch(void* const* d_in, const int* in_sizes, int n_in,
                              void* d_out, int out_size, void* d_ws, size_t ws_size,
                              hipStream_t stream) {
  const float* x      = (const float*)d_in[0];
  const float* w_kv   = (const float*)d_in[1];
  const float* w_z    = (const float*)d_in[2];
  const float* b_comp = (const float*)d_in[3];
  const float* w_dq   = (const float*)d_in[4];
  const float* w_uq   = (const float*)d_in[5];
  const float* o_down = (const float*)d_in[6];
  const float* o_up   = (const float*)d_in[7];
  const float* kv_g   = (const float*)d_in[8];
  const float* kv_b   = (const float*)d_in[9];
  const float* q_g    = (const float*)d_in[10];
  const float* q_b    = (const float*)d_in[11];
  const float* sinkl  = (const float*)d_in[12];
  char* ws = (char*)d_ws;
  bf16*   WCZQ  = (bf16*)(ws + OFF_WCZQ);
  bf16*   WUQ   = (bf16*)(ws + OFF_WUQ);
  bf16*   DOWNB = (bf16*)(ws + OFF_DOWNB);
  bf16*   WUP   = (bf16*)(ws + OFF_WUP);
  bf16*   W2T   = (bf16*)(ws + OFF_W2T);
  bf16*   KC    = (bf16*)(ws + OFF_KC);
  bf16*   VT    = (bf16*)(ws + OFF_VT);
  float2* ROPE  = (float2*)(ws + OFF_ROPE);
  bf16*   XB    = (bf16*)(ws + OFF_XB);
  bf16*   CZQ   = (bf16*)(ws + OFF_CZQ);
  bf16*   QF    = (bf16*)(ws + OFF_QF);
  bf16*   ATT   = (bf16*)(ws + OFF_XB);
  float*  OUT   = (float*)d_out;

  // weight prep
  transpose_f32_bf16<<<dim3(4, 64), 256, 0, stream>>>(w_kv, WCZQ, 2048, 128);
  transpose_f32_bf16<<<dim3(4, 64), 256, 0, stream>>>(w_z, WCZQ + 128 * 2048, 2048, 128);
  transpose_f32_bf16<<<dim3(16, 64), 256, 0, stream>>>(w_dq, WCZQ + 256 * 2048, 2048, 512);
  transpose_f32_bf16<<<dim3(64, 16), 256, 0, stream>>>(w_uq, WUQ, 512, 2048);
  transpose_f32_bf16<<<dim3(64, 64), 256, 0, stream>>>(o_up, WUP, 2048, 2048);
  cvt_bf16_k<<<512, 256, 0, stream>>>(o_down, DOWNB);
  cvt_bf16_k<<<16384, 256, 0, stream>>>(x, XB);
  rope_table_k<<<1024, 256, 0, stream>>>(ROPE);
  // fused [c_proj | z | q_mid] = x @ [w_kv | w_z | w_dq]   (16384 x 768)
  gemm8p<1><<<192, 512, 0, stream>>>(XB, DM, WCZQ, DM, CZQ, 768, DM, 3);
  // compression + kv LN (writes K row-major and V^T)
  compress_k<<<128, 512, 0, stream>>>(CZQ, 768, b_comp, kv_g, kv_b, KC, VT);
  // q = q_mid @ w_uq   (16384 x 2048, K=512)
  gemm8p<1><<<512, 512, 0, stream>>>(CZQ + 256, 768, WUQ, 512, QF, DM, 512, 8);
  // attention (fused q-LN + rope)
  attn_k<<<dim3(64, 16, 2), 256, 0, stream>>>(QF, KC, VT, sinkl, q_g, q_b, ROPE, ATT);
  // W2T = up^T @ down (per group)
  for (int g = 0; g < 4; g++)
    gemm_bt<1><<<64, 256, 0, stream>>>(WUP + g * 512, DM, DOWNB + (size_t)g * 512 * 512, 512,
                                       W2T + g * 512, DM, 512, 4);
  // final: OUT = ATT @ W2T^T  (16384 x 2048, K=2048)
  gemm8p<0><<<512, 512, 0, stream>>>(ATT, DM, W2T, DM, OUT, DM, DM, 8);
}

// Round 9
// 445.553 us; speedup vs baseline: 1.0178x; 1.0178x over previous
//
#include <hip/hip_runtime.h>
#include <hip/hip_bf16.h>

using bf16 = __hip_bfloat16;
typedef __attribute__((ext_vector_type(8))) short bf16x8;
typedef __attribute__((ext_vector_type(4))) float f32x4;

#define DM 2048

// ---- workspace offsets (bytes) ----
#define OFF_WCZQ  0x00000000ULL  // 768x2048 bf16 (w_kv^T | w_z^T | w_dq^T)
#define OFF_WUQ   0x00300000ULL  // 2048x512 bf16
#define OFF_DOWNB 0x00500000ULL  // 4x512x512 bf16 (o_down, plain cvt)
#define OFF_WUP   0x00700000ULL  // 2048x2048 bf16 (o_up^T)
#define OFF_W2T   0x00F00000ULL  // 2048x2048 bf16 (fused down*up, transposed)
#define OFF_KC    0x01700000ULL  // 2*64*128 bf16
#define OFF_VT    0x01710000ULL  // 2*128*64 bf16 (V transposed per batch)
#define OFF_ROPE  0x01720000ULL  // 8192*32 float2
#define OFF_XB    0x01A00000ULL  // 16384x2048 bf16 (x), reused for attn-out
#define OFF_CZQ   0x05A00000ULL  // 16384x768 bf16 (c_proj | z | q_mid)
#define OFF_QF    0x07300000ULL  // 16384x2048 bf16

__device__ __forceinline__ void async16(const void* g, void* l) {
  __builtin_amdgcn_global_load_lds(
      (const __attribute__((address_space(1))) unsigned int*)g,
      (__attribute__((address_space(3))) unsigned int*)l, 16, 0, 0);
}

__device__ __forceinline__ f32x4 mfma16(bf16x8 a, bf16x8 b, f32x4 c) {
  return __builtin_amdgcn_mfma_f32_16x16x32_bf16(a, b, c, 0, 0, 0);
}

__device__ __forceinline__ float b2f(short u) {
  unsigned x = ((unsigned)(unsigned short)u) << 16;
  return __builtin_bit_cast(float, x);
}
__device__ __forceinline__ short f2bs(float f) {
  return __builtin_bit_cast(short, __float2bfloat16(f));
}

#define SB0 __builtin_amdgcn_sched_barrier(0)

// ---------------- weight transpose: src (K x N) f32 -> dst (N x K) bf16 ----------------
__global__ __launch_bounds__(256) void transpose_f32_bf16(
    const float* __restrict__ src, bf16* __restrict__ dst, int K, int N) {
  __shared__ float t[32][33];
  const int tn0 = blockIdx.x * 32, tk0 = blockIdx.y * 32;
  const int lx = threadIdx.x & 31, ly = threadIdx.x >> 5;
#pragma unroll
  for (int p = 0; p < 4; p++) {
    int k = tk0 + ly + p * 8, n = tn0 + lx;
    if (k < K && n < N) t[ly + p * 8][lx] = src[(size_t)k * N + n];
  }
  __syncthreads();
#pragma unroll
  for (int p = 0; p < 4; p++) {
    int n = tn0 + ly + p * 8, k = tk0 + lx;
    if (n < N && k < K) dst[(size_t)n * K + k] = __float2bfloat16(t[lx][ly + p * 8]);
  }
}

// ---------------- f32 -> bf16 bulk convert ----------------
__global__ __launch_bounds__(256) void cvt_bf16_k(const float* __restrict__ in, bf16* __restrict__ out) {
  size_t i = ((size_t)blockIdx.x * 256 + threadIdx.x) * 8;
  float4 a = *(const float4*)(in + i);
  float4 b = *(const float4*)(in + i + 4);
  struct alignas(16) B8 { bf16 v[8]; } r;
  r.v[0] = __float2bfloat16(a.x); r.v[1] = __float2bfloat16(a.y);
  r.v[2] = __float2bfloat16(a.z); r.v[3] = __float2bfloat16(a.w);
  r.v[4] = __float2bfloat16(b.x); r.v[5] = __float2bfloat16(b.y);
  r.v[6] = __float2bfloat16(b.z); r.v[7] = __float2bfloat16(b.w);
  *(B8*)(out + i) = r;
}

// ---------------- rope cos/sin table [8192][32] ----------------
__global__ __launch_bounds__(256) void rope_table_k(float2* __restrict__ tab) {
  int idx = blockIdx.x * 256 + threadIdx.x;
  int s = idx >> 5, i = idx & 31;
  double f = pow(10000.0, -((double)(2 * i)) / 64.0);
  double a = (double)s * f;
  tab[idx] = make_float2((float)cos(a), (float)sin(a));
}

// ================= 256x256 8-phase GEMM: C = A(MxK,lda) @ Bt(NxK,ldb)^T =================
// 512 thr / 8 waves (2Mx4N); BK=64 as 2 k-halves; LDS [2dbuf][A,B][2kh][256][32] = 128 KiB.
// Counted vmcnt(4) at 2 sync points per K-tile; max 8 outstanding global_load_lds/wave.
// T2 bank swizzle: 16B unit u of row r stored at u^((r>>1)&3) — applied by permuting the
// GLOBAL source per 16B unit (linear LDS dest, rule #21) and the read-base unit index.
// Turns the 8-way quarter-wave ds_read_b128 conflict into 2-way (free).
// STABLE STRUCTURE — deeper pipelines (12 outstanding) were replay-nondeterministic; do not deepen.
template <int OUT_BF16>
__global__ __launch_bounds__(512, 2) void gemm8p(
    const bf16* __restrict__ A, int lda,
    const bf16* __restrict__ Bt, int ldb,
    void* __restrict__ Cp, int ldc, int K, int ntiles) {
  __shared__ bf16 lds[2][2][2][256][32];  // 131072 B
  const int tid = threadIdx.x;
  const int lane = tid & 63, wid = tid >> 6;
  const int wr = wid >> 2, wc = wid & 3;
  const int wgid = (blockIdx.x & 7) * (gridDim.x >> 3) + (blockIdx.x >> 3);
  const int mt = wgid / ntiles, nt = wgid % ntiles;
  const int srow = tid >> 2;
  const int sunit = (tid & 3) ^ ((tid >> 3) & 3);  // source unit pre-swizzled
  const bf16* gA = A + (size_t)(mt * 256 + srow) * lda + (sunit << 3);
  const bf16* gB = Bt + (size_t)(nt * 256 + srow) * ldb + (sunit << 3);
  char* ldsA = (char*)lds + tid * 16;
  char* ldsB = (char*)lds + 32768 + tid * 16;

#define STAGE_A(dd, h, kc) do { \
    const bf16* _s = gA + (kc) + (h) * 32; \
    char* _d = ldsA + (dd) * 65536 + (h) * 16384; \
    async16(_s, _d); \
    async16(_s + (size_t)128 * lda, _d + 8192); } while (0)
#define STAGE_B(dd, h, kc) do { \
    const bf16* _s = gB + (kc) + (h) * 32; \
    char* _d = ldsB + (dd) * 65536 + (h) * 16384; \
    async16(_s, _d); \
    async16(_s + (size_t)128 * ldb, _d + 8192); } while (0)

  const int l15 = lane & 15, g = lane >> 4;
  const int gsw = g ^ ((l15 >> 1) & 3);  // swizzled read unit (row-parity term; invariant across m/n/wr/wc steps)
  const char* ardb = (char*)lds + (size_t)(wr * 128 + l15) * 64 + (gsw << 4);
  const char* brdb = (char*)lds + 32768 + (size_t)(wc * 64 + l15) * 64 + (gsw << 4);

  f32x4 acc[8][4] = {};
  // prologue: stage K-tile 0 (FIFO: A-h0, B-h0, A-h1, B-h1 = 8 loads)
  STAGE_A(0, 0, 0); STAGE_B(0, 0, 0); STAGE_A(0, 1, 0); STAGE_B(0, 1, 0);

  const int nkt = K >> 6;
  for (int t = 0; t < nkt; ++t) {
    const int d = t & 1;
    const char* aB = ardb + d * 65536;
    const char* bB = brdb + d * 65536;
    const int kn = (t + 1) << 6;
    const bool pf = (t + 1) < nkt;
    bf16x8 a[8], b0, b1;
    // ---- P1: sync (A-h0,B-h0 landed), stage A-h0', compute (h0, n0/n1) ----
    SB0;
    asm volatile("s_waitcnt vmcnt(4)" ::: "memory");
    __builtin_amdgcn_s_barrier();
    asm volatile("" ::: "memory");
    SB0;
    if (pf) STAGE_A(d ^ 1, 0, kn);
#pragma unroll
    for (int m = 0; m < 8; m++) a[m] = *(const bf16x8*)(aB + m * 1024);
    b0 = *(const bf16x8*)(bB);
    b1 = *(const bf16x8*)(bB + 1024);
    __builtin_amdgcn_s_setprio(1);
#pragma unroll
    for (int m = 0; m < 8; m++) {
      acc[m][0] = mfma16(a[m], b0, acc[m][0]);
      acc[m][1] = mfma16(a[m], b1, acc[m][1]);
    }
    __builtin_amdgcn_s_setprio(0);
    // ---- P2: stage B-h0', compute (h0, n2/n3) ----
    if (pf) STAGE_B(d ^ 1, 0, kn);
    b0 = *(const bf16x8*)(bB + 2048);
    b1 = *(const bf16x8*)(bB + 3072);
    __builtin_amdgcn_s_setprio(1);
#pragma unroll
    for (int m = 0; m < 8; m++) {
      acc[m][2] = mfma16(a[m], b0, acc[m][2]);
      acc[m][3] = mfma16(a[m], b1, acc[m][3]);
    }
    __builtin_amdgcn_s_setprio(0);
    // ---- P3: sync (A-h1,B-h1 landed), stage A-h1', compute (h1, n0/n1) ----
    SB0;
    if (pf) asm volatile("s_waitcnt vmcnt(4)" ::: "memory");
    else    asm volatile("s_waitcnt vmcnt(0)" ::: "memory");
    __builtin_amdgcn_s_barrier();
    asm volatile("" ::: "memory");
    SB0;
    if (pf) STAGE_A(d ^ 1, 1, kn);
#pragma unroll
    for (int m = 0; m < 8; m++) a[m] = *(const bf16x8*)(aB + 16384 + m * 1024);
    b0 = *(const bf16x8*)(bB + 16384);
    b1 = *(const bf16x8*)(bB + 16384 + 1024);
    __builtin_amdgcn_s_setprio(1);
#pragma unroll
    for (int m = 0; m < 8; m++) {
      acc[m][0] = mfma16(a[m], b0, acc[m][0]);
      acc[m][1] = mfma16(a[m], b1, acc[m][1]);
    }
    __builtin_amdgcn_s_setprio(0);
    // ---- P4: stage B-h1', compute (h1, n2/n3) ----
    if (pf) STAGE_B(d ^ 1, 1, kn);
    b0 = *(const bf16x8*)(bB + 16384 + 2048);
    b1 = *(const bf16x8*)(bB + 16384 + 3072);
    __builtin_amdgcn_s_setprio(1);
#pragma unroll
    for (int m = 0; m < 8; m++) {
      acc[m][2] = mfma16(a[m], b0, acc[m][2]);
      acc[m][3] = mfma16(a[m], b1, acc[m][3]);
    }
    __builtin_amdgcn_s_setprio(0);
  }
#undef STAGE_A
#undef STAGE_B

  const int r4 = (lane >> 4) << 2;
  const size_t row0 = (size_t)mt * 256 + wr * 128;
  const int col0 = nt * 256 + wc * 64;
#pragma unroll
  for (int m = 0; m < 8; m++)
#pragma unroll
    for (int n = 0; n < 4; n++)
#pragma unroll
      for (int j = 0; j < 4; j++) {
        size_t row = row0 + m * 16 + r4 + j;
        size_t col = (size_t)col0 + n * 16 + l15;
        if (OUT_BF16) ((bf16*)Cp)[row * ldc + col] = __float2bfloat16(acc[m][n][j]);
        else          ((float*)Cp)[row * ldc + col] = acc[m][n][j];
      }
}

// ---------------- generic bf16 GEMM (128² m97-style) — small W2T prep ----------------
template <int OUT_BF16>
__global__ __launch_bounds__(256) void gemm_bt(
    const bf16* __restrict__ A, int lda,
    const bf16* __restrict__ Bt, int ldb,
    void* __restrict__ Cp, int ldc, int K, int ntiles) {
  __shared__ bf16 As[128 * 32];
  __shared__ bf16 Bs[128 * 32];
  const int tid = threadIdx.x;
  const int wave = tid >> 6, lane = tid & 63;
  const int wgid = (blockIdx.x & 7) * (gridDim.x >> 3) + (blockIdx.x >> 3);
  const int mt = wgid / ntiles, nt = wgid % ntiles;
  const int srow = tid >> 2, scol = (tid & 3) << 3;
  const bf16* ag = A + (size_t)(mt * 128 + srow) * lda + scol;
  const bf16* bg = Bt + (size_t)(nt * 128 + srow) * ldb + scol;
  char* asw = (char*)As + wave * 1024;
  char* bsw = (char*)Bs + wave * 1024;
  const int l15 = lane & 15, lk = (lane >> 4) << 3;
  const int wm = (wave >> 1) * 64, wn = (wave & 1) * 64;
  f32x4 acc[4][4] = {};
  for (int kt = 0; kt < K; kt += 32) {
    __syncthreads();
    async16(ag + kt, asw);
    async16(ag + kt + (size_t)64 * lda, asw + 4096);
    async16(bg + kt, bsw);
    async16(bg + kt + (size_t)64 * ldb, bsw + 4096);
    __syncthreads();
    bf16x8 af[4], bfr[4];
#pragma unroll
    for (int m = 0; m < 4; m++)
      af[m] = *(const bf16x8*)((const char*)As + (size_t)((wm + m * 16 + l15) * 32 + lk) * 2);
#pragma unroll
    for (int n = 0; n < 4; n++)
      bfr[n] = *(const bf16x8*)((const char*)Bs + (size_t)((wn + n * 16 + l15) * 32 + lk) * 2);
#pragma unroll
    for (int m = 0; m < 4; m++)
#pragma unroll
      for (int n = 0; n < 4; n++)
        acc[m][n] = mfma16(af[m], bfr[n], acc[m][n]);
  }
  const int r4 = (lane >> 4) << 2;
#pragma unroll
  for (int m = 0; m < 4; m++)
#pragma unroll
    for (int n = 0; n < 4; n++)
#pragma unroll
      for (int j = 0; j < 4; j++) {
        size_t row = (size_t)mt * 128 + wm + m * 16 + r4 + j;
        size_t col = (size_t)nt * 128 + wn + n * 16 + l15;
        if (OUT_BF16) ((bf16*)Cp)[row * ldc + col] = __float2bfloat16(acc[m][n][j]);
        else          ((float*)Cp)[row * ldc + col] = acc[m][n][j];
      }
}

// ---------------- compression: softmax over M + weighted sum, LN; writes K and V^T ----------------
__global__ __launch_bounds__(512) void compress_k(
    const bf16* __restrict__ cz, int ldcz, const float* __restrict__ b_comp,
    const float* __restrict__ gamma, const float* __restrict__ beta,
    bf16* __restrict__ k_comp, bf16* __restrict__ vt) {
  const int blk = blockIdx.x;
  const int t = threadIdx.x, c = t & 127, qtr = t >> 7;
  const size_t t0 = (size_t)blk * 128;
  float num = 0.f, den = 0.f;
  for (int m = qtr * 32; m < qtr * 32 + 32; m++) {
    const bf16* r = cz + (t0 + m) * ldcz;
    float w = expf(__bfloat162float(r[128 + c]) + b_comp[m * 128 + c]);
    den += w;
    num += w * __bfloat162float(r[c]);
  }
  __shared__ float sn[4][128], sd[4][128], sv[128];
  sn[qtr][c] = num;
  sd[qtr][c] = den;
  __syncthreads();
  if (qtr == 0)
    sv[c] = (sn[0][c] + sn[1][c] + sn[2][c] + sn[3][c]) /
            (sd[0][c] + sd[1][c] + sd[2][c] + sd[3][c]);
  __syncthreads();
  if (qtr == 0) {
    float v = sv[c];
    float mu = 0.f;
    for (int i = 0; i < 128; i++) mu += sv[i];
    mu *= (1.f / 128.f);
    float var = 0.f;
    for (int i = 0; i < 128; i++) { float d = sv[i] - mu; var += d * d; }
    var *= (1.f / 128.f);
    float kc = (v - mu) * rsqrtf(var + 1e-6f) * gamma[c] + beta[c];
    const int b = blk >> 6, kb = blk & 63;
    k_comp[(size_t)blk * 128 + c] = __float2bfloat16(kc);
    vt[(size_t)b * 8192 + c * 64 + kb] = __float2bfloat16(v);
  }
}

// ---------------- attention: fused q-LN+RoPE, K/V^T direct from global, swizzled LDS ----------------
__global__ __launch_bounds__(256) void attn_k(
    const bf16* __restrict__ qln, const bf16* __restrict__ kc,
    const bf16* __restrict__ vt, const float* __restrict__ sink_logits,
    const float* __restrict__ gamma, const float* __restrict__ beta,
    const float2* __restrict__ rope, bf16* __restrict__ out) {
  __shared__ bf16 Qs[128 * 128];  // swizzled rows; P[128][64] overlays after QK^T
  const int qt = blockIdx.x, hh = blockIdx.y, b = blockIdx.z;
  const int nk = qt + 1;
  const int ntk = (nk + 15) >> 4;
  const int nkk = (nk + 31) >> 5;
  const int tid = threadIdx.x, wave = tid >> 6, lane = tid & 63;
  const int l15 = lane & 15, g = lane >> 4;
  const size_t t0 = (size_t)b * 8192 + (size_t)qt * 128;
  const bf16* kbase = kc + (size_t)b * 64 * 128;
  const bf16* vbase = vt + (size_t)b * 128 * 64;

  {
    const int q = tid >> 1, hf = tid & 1;
    const bf16* gq = qln + (t0 + q) * 2048 + hh * 128 + hf * 64;
    bf16x8 r[8];
#pragma unroll
    for (int i = 0; i < 8; i++) r[i] = *(const bf16x8*)(gq + i * 8);
    float sum = 0.f;
#pragma unroll
    for (int i = 0; i < 8; i++)
#pragma unroll
      for (int j = 0; j < 8; j++) sum += b2f(r[i][j]);
    sum += __shfl_xor(sum, 1);
    const float mu = sum * (1.f / 128.f);
    float var = 0.f;
#pragma unroll
    for (int i = 0; i < 8; i++)
#pragma unroll
      for (int j = 0; j < 8; j++) { float d = b2f(r[i][j]) - mu; var += d * d; }
    var += __shfl_xor(var, 1);
    const float inv = rsqrtf(var * (1.f / 128.f) + 1e-6f);
    const int c0 = hf * 64;
#pragma unroll
    for (int i = 0; i < 8; i++) {
      float y[8];
#pragma unroll
      for (int j = 0; j < 8; j++) {
        int ch = c0 + i * 8 + j;
        y[j] = (b2f(r[i][j]) - mu) * inv * gamma[ch] + beta[ch];
      }
      if (hf) {
#pragma unroll
        for (int j = 0; j < 8; j += 2) {
          float2 cs = rope[((size_t)qt * 128 + q) * 32 + i * 4 + (j >> 1)];
          float e = y[j], o = y[j + 1];
          y[j] = e * cs.x - o * cs.y;
          y[j + 1] = e * cs.y + o * cs.x;
        }
      }
      bf16x8 w;
#pragma unroll
      for (int j = 0; j < 8; j++) w[j] = f2bs(y[j]);
      *(bf16x8*)(Qs + q * 128 + ((hf * 8 + (i ^ (q & 7))) << 3)) = w;
    }
  }
  __syncthreads();

  bf16x8 af[2][4];
#pragma unroll
  for (int m = 0; m < 2; m++) {
    const int q = wave * 32 + m * 16 + l15;
#pragma unroll
    for (int kk = 0; kk < 4; kk++) {
      const int u = (kk * 4 + g) ^ (q & 7);
      af[m][kk] = *(const bf16x8*)(Qs + q * 128 + u * 8);
    }
  }
  __syncthreads();  // Qs dead; safe to overlay P

  f32x4 sacc[2][4] = {};
#pragma unroll
  for (int n = 0; n < 4; n++) {
    if (n < ntk) {
      const bf16* kr = kbase + (n * 16 + l15) * 128 + g * 8;
      bf16x8 b0 = *(const bf16x8*)(kr);
      bf16x8 b1 = *(const bf16x8*)(kr + 32);
      bf16x8 b2 = *(const bf16x8*)(kr + 64);
      bf16x8 b3 = *(const bf16x8*)(kr + 96);
      __builtin_amdgcn_s_setprio(1);
      sacc[0][n] = mfma16(af[0][0], b0, sacc[0][n]);
      sacc[1][n] = mfma16(af[1][0], b0, sacc[1][n]);
      sacc[0][n] = mfma16(af[0][1], b1, sacc[0][n]);
      sacc[1][n] = mfma16(af[1][1], b1, sacc[1][n]);
      sacc[0][n] = mfma16(af[0][2], b2, sacc[0][n]);
      sacc[1][n] = mfma16(af[1][2], b2, sacc[1][n]);
      sacc[0][n] = mfma16(af[0][3], b3, sacc[0][n]);
      sacc[1][n] = mfma16(af[1][3], b3, sacc[1][n]);
      __builtin_amdgcn_s_setprio(0);
    }
  }

  const float sink = expf(sink_logits[hh]);
  const float scale = 0.088388347648318447f;  // 1/sqrt(128)
  bf16* P = Qs;
#pragma unroll
  for (int m = 0; m < 2; m++) {
    float pv[4][4];
    float rs[4] = {0.f, 0.f, 0.f, 0.f};
#pragma unroll
    for (int n = 0; n < 4; n++) {
      int key = n * 16 + l15;
#pragma unroll
      for (int j = 0; j < 4; j++) {
        float p = (key < nk) ? expf(sacc[m][n][j] * scale) : 0.f;
        pv[n][j] = p;
        rs[j] += p;
      }
    }
#pragma unroll
    for (int j = 0; j < 4; j++) {
      float v = rs[j];
      v += __shfl_xor(v, 1); v += __shfl_xor(v, 2);
      v += __shfl_xor(v, 4); v += __shfl_xor(v, 8);
      rs[j] = 1.0f / (v + sink);
    }
    const int row0 = wave * 32 + m * 16 + (g << 2);
#pragma unroll
    for (int n = 0; n < 4; n++)
#pragma unroll
      for (int j = 0; j < 4; j++) {
        int q = row0 + j;
        int k = n * 16 + l15;
        P[q * 64 + ((((k >> 3) ^ (q & 7)) << 3) | (k & 7))] =
            __float2bfloat16(pv[n][j] * rs[j]);
      }
  }
  // no barrier: PV reads only this wave's own P rows

  f32x4 oacc[2][8] = {};
#pragma unroll
  for (int kk = 0; kk < 2; kk++) {
    if (kk < nkk) {
      bf16x8 pa[2];
#pragma unroll
      for (int m = 0; m < 2; m++) {
        const int q = wave * 32 + m * 16 + l15;
        const int u = (kk * 4 + g) ^ (q & 7);
        pa[m] = *(const bf16x8*)(P + q * 64 + u * 8);
      }
#pragma unroll
      for (int n = 0; n < 8; n++) {
        bf16x8 vb = *(const bf16x8*)(vbase + (n * 16 + l15) * 64 + kk * 32 + g * 8);
        __builtin_amdgcn_s_setprio(1);
        oacc[0][n] = mfma16(pa[0], vb, oacc[0][n]);
        oacc[1][n] = mfma16(pa[1], vb, oacc[1][n]);
        __builtin_amdgcn_s_setprio(0);
      }
    }
  }

  bf16* ob = out + t0 * 2048 + hh * 128;
  const int r4 = g << 2;
#pragma unroll
  for (int m = 0; m < 2; m++)
#pragma unroll
    for (int n = 0; n < 8; n++)
#pragma unroll
      for (int j = 0; j < 4; j++)
        ob[(size_t)(wave * 32 + m * 16 + r4 + j) * 2048 + n * 16 + l15] =
            __float2bfloat16(oacc[m][n][j]);
}

extern "C" void kernel_launch(void* const* d_in, const int* in_sizes, int n_in,
                              void* d_out, int out_size, void* d_ws, size_t ws_size,
                              hipStream_t stream) {
  const float* x      = (const float*)d_in[0];
  const float* w_kv   = (const float*)d_in[1];
  const float* w_z    = (const float*)d_in[2];
  const float* b_comp = (const float*)d_in[3];
  const float* w_dq   = (const float*)d_in[4];
  const float* w_uq   = (const float*)d_in[5];
  const float* o_down = (const float*)d_in[6];
  const float* o_up   = (const float*)d_in[7];
  const float* kv_g   = (const float*)d_in[8];
  const float* kv_b   = (const float*)d_in[9];
  const float* q_g    = (const float*)d_in[10];
  const float* q_b    = (const float*)d_in[11];
  const float* sinkl  = (const float*)d_in[12];
  char* ws = (char*)d_ws;
  bf16*   WCZQ  = (bf16*)(ws + OFF_WCZQ);
  bf16*   WUQ   = (bf16*)(ws + OFF_WUQ);
  bf16*   DOWNB = (bf16*)(ws + OFF_DOWNB);
  bf16*   WUP   = (bf16*)(ws + OFF_WUP);
  bf16*   W2T   = (bf16*)(ws + OFF_W2T);
  bf16*   KC    = (bf16*)(ws + OFF_KC);
  bf16*   VT    = (bf16*)(ws + OFF_VT);
  float2* ROPE  = (float2*)(ws + OFF_ROPE);
  bf16*   XB    = (bf16*)(ws + OFF_XB);
  bf16*   CZQ   = (bf16*)(ws + OFF_CZQ);
  bf16*   QF    = (bf16*)(ws + OFF_QF);
  bf16*   ATT   = (bf16*)(ws + OFF_XB);
  float*  OUT   = (float*)d_out;

  // weight prep
  transpose_f32_bf16<<<dim3(4, 64), 256, 0, stream>>>(w_kv, WCZQ, 2048, 128);
  transpose_f32_bf16<<<dim3(4, 64), 256, 0, stream>>>(w_z, WCZQ + 128 * 2048, 2048, 128);
  transpose_f32_bf16<<<dim3(16, 64), 256, 0, stream>>>(w_dq, WCZQ + 256 * 2048, 2048, 512);
  transpose_f32_bf16<<<dim3(64, 16), 256, 0, stream>>>(w_uq, WUQ, 512, 2048);
  transpose_f32_bf16<<<dim3(64, 64), 256, 0, stream>>>(o_up, WUP, 2048, 2048);
  cvt_bf16_k<<<512, 256, 0, stream>>>(o_down, DOWNB);
  cvt_bf16_k<<<16384, 256, 0, stream>>>(x, XB);
  rope_table_k<<<1024, 256, 0, stream>>>(ROPE);
  // fused [c_proj | z | q_mid] = x @ [w_kv | w_z | w_dq]   (16384 x 768)
  gemm8p<1><<<192, 512, 0, stream>>>(XB, DM, WCZQ, DM, CZQ, 768, DM, 3);
  // compression + kv LN (writes K row-major and V^T)
  compress_k<<<128, 512, 0, stream>>>(CZQ, 768, b_comp, kv_g, kv_b, KC, VT);
  // q = q_mid @ w_uq   (16384 x 2048, K=512)
  gemm8p<1><<<512, 512, 0, stream>>>(CZQ + 256, 768, WUQ, 512, QF, DM, 512, 8);
  // attention (fused q-LN + rope)
  attn_k<<<dim3(64, 16, 2), 256, 0, stream>>>(QF, KC, VT, sinkl, q_g, q_b, ROPE, ATT);
  // W2T = up^T @ down (per group)
  for (int g = 0; g < 4; g++)
    gemm_bt<1><<<64, 256, 0, stream>>>(WUP + g * 512, DM, DOWNB + (size_t)g * 512 * 512, 512,
                                       W2T + g * 512, DM, 512, 4);
  // final: OUT = ATT @ W2T^T  (16384 x 2048, K=2048)
  gemm8p<0><<<512, 512, 0, stream>>>(ATT, DM, W2T, DM, OUT, DM, DM, 8);
}

// Round 10
// 445.366 us; speedup vs baseline: 1.0182x; 1.0004x over previous
//
#include <hip/hip_runtime.h>
#include <hip/hip_bf16.h>

using bf16 = __hip_bfloat16;
typedef __attribute__((ext_vector_type(8))) short bf16x8;
typedef __attribute__((ext_vector_type(4))) float f32x4;

#define DM 2048

// ---- workspace offsets (bytes) ----
#define OFF_WCZQ  0x00000000ULL  // 768x2048 bf16 (w_kv^T | w_z^T | w_dq^T)
#define OFF_WUQ   0x00300000ULL  // 2048x512 bf16
#define OFF_DOWNB 0x00500000ULL  // 4x512x512 bf16 (o_down, plain cvt)
#define OFF_WUP   0x00700000ULL  // 2048x2048 bf16 (o_up^T)
#define OFF_W2T   0x00F00000ULL  // 2048x2048 bf16 (fused down*up, transposed)
#define OFF_KC    0x01700000ULL  // 2*64*128 bf16
#define OFF_VT    0x01710000ULL  // 2*128*64 bf16 (V transposed per batch)
#define OFF_ROPE  0x01720000ULL  // 8192*32 float2
#define OFF_XB    0x01A00000ULL  // 16384x2048 bf16 (x), reused for attn-out
#define OFF_CZQ   0x05A00000ULL  // 16384x768 bf16 (c_proj | z | q_mid)
#define OFF_QF    0x07300000ULL  // 16384x2048 bf16

__device__ __forceinline__ void async16(const void* g, void* l) {
  __builtin_amdgcn_global_load_lds(
      (const __attribute__((address_space(1))) unsigned int*)g,
      (__attribute__((address_space(3))) unsigned int*)l, 16, 0, 0);
}

__device__ __forceinline__ f32x4 mfma16(bf16x8 a, bf16x8 b, f32x4 c) {
  return __builtin_amdgcn_mfma_f32_16x16x32_bf16(a, b, c, 0, 0, 0);
}

__device__ __forceinline__ float b2f(short u) {
  unsigned x = ((unsigned)(unsigned short)u) << 16;
  return __builtin_bit_cast(float, x);
}
__device__ __forceinline__ short f2bs(float f) {
  return __builtin_bit_cast(short, __float2bfloat16(f));
}

#define SB0 __builtin_amdgcn_sched_barrier(0)

// ---------------- weight transpose: src (K x N) f32 -> dst (N x K) bf16 ----------------
__global__ __launch_bounds__(256) void transpose_f32_bf16(
    const float* __restrict__ src, bf16* __restrict__ dst, int K, int N) {
  __shared__ float t[32][33];
  const int tn0 = blockIdx.x * 32, tk0 = blockIdx.y * 32;
  const int lx = threadIdx.x & 31, ly = threadIdx.x >> 5;
#pragma unroll
  for (int p = 0; p < 4; p++) {
    int k = tk0 + ly + p * 8, n = tn0 + lx;
    if (k < K && n < N) t[ly + p * 8][lx] = src[(size_t)k * N + n];
  }
  __syncthreads();
#pragma unroll
  for (int p = 0; p < 4; p++) {
    int n = tn0 + ly + p * 8, k = tk0 + lx;
    if (n < N && k < K) dst[(size_t)n * K + k] = __float2bfloat16(t[lx][ly + p * 8]);
  }
}

// ---------------- f32 -> bf16 bulk convert ----------------
__global__ __launch_bounds__(256) void cvt_bf16_k(const float* __restrict__ in, bf16* __restrict__ out) {
  size_t i = ((size_t)blockIdx.x * 256 + threadIdx.x) * 8;
  float4 a = *(const float4*)(in + i);
  float4 b = *(const float4*)(in + i + 4);
  struct alignas(16) B8 { bf16 v[8]; } r;
  r.v[0] = __float2bfloat16(a.x); r.v[1] = __float2bfloat16(a.y);
  r.v[2] = __float2bfloat16(a.z); r.v[3] = __float2bfloat16(a.w);
  r.v[4] = __float2bfloat16(b.x); r.v[5] = __float2bfloat16(b.y);
  r.v[6] = __float2bfloat16(b.z); r.v[7] = __float2bfloat16(b.w);
  *(B8*)(out + i) = r;
}

// ---------------- rope cos/sin table [8192][32] ----------------
__global__ __launch_bounds__(256) void rope_table_k(float2* __restrict__ tab) {
  int idx = blockIdx.x * 256 + threadIdx.x;
  int s = idx >> 5, i = idx & 31;
  double f = pow(10000.0, -((double)(2 * i)) / 64.0);
  double a = (double)s * f;
  tab[idx] = make_float2((float)cos(a), (float)sin(a));
}

// ================= 256x256 8-phase GEMM: C = A(MxK,lda) @ Bt(NxK,ldb)^T =================
// 1024 thr / 16 waves (4Mx4N, 4 waves/SIMD for latency-hiding TLP); BK=64 as 2 k-halves;
// LDS [2dbuf][A,B][2kh][256][32] = 128 KiB. One async16 per thread covers a full 16 KB
// half-tile. Counted vmcnt(2) at the 2 sync points per K-tile; max 4 outstanding/wave.
// T2 bank swizzle: 16B unit u of row r stored at u^((r>>1)&3), via pre-swizzled global
// source (linear LDS dest) + swizzled read base. SYNC SKELETON = R3-stable; do not deepen.
template <int OUT_BF16>
__global__ __launch_bounds__(1024, 1) void gemm8p(
    const bf16* __restrict__ A, int lda,
    const bf16* __restrict__ Bt, int ldb,
    void* __restrict__ Cp, int ldc, int K, int ntiles) {
  __shared__ bf16 lds[2][2][2][256][32];  // 131072 B
  const int tid = threadIdx.x;
  const int lane = tid & 63, wid = tid >> 6;
  const int wr = wid >> 2, wc = wid & 3;  // 4x4 wave grid, 64x64 out per wave
  const int wgid = (blockIdx.x & 7) * (gridDim.x >> 3) + (blockIdx.x >> 3);
  const int mt = wgid / ntiles, nt = wgid % ntiles;
  const int srow = tid >> 2;                       // 0..255
  const int sunit = (tid & 3) ^ ((tid >> 3) & 3);  // source unit pre-swizzled
  const bf16* gA = A + (size_t)(mt * 256 + srow) * lda + (sunit << 3);
  const bf16* gB = Bt + (size_t)(nt * 256 + srow) * ldb + (sunit << 3);
  char* ldsA = (char*)lds + tid * 16;
  char* ldsB = (char*)lds + 32768 + tid * 16;

#define STAGE_A(dd, h, kc) async16(gA + (kc) + (h) * 32, ldsA + (dd) * 65536 + (h) * 16384)
#define STAGE_B(dd, h, kc) async16(gB + (kc) + (h) * 32, ldsB + (dd) * 65536 + (h) * 16384)

  const int l15 = lane & 15, g = lane >> 4;
  const int gsw = g ^ ((l15 >> 1) & 3);  // swizzled read unit
  const char* ardb = (char*)lds + (size_t)(wr * 64 + l15) * 64 + (gsw << 4);
  const char* brdb = (char*)lds + 32768 + (size_t)(wc * 64 + l15) * 64 + (gsw << 4);

  f32x4 acc[4][4] = {};
  // prologue: stage K-tile 0 (FIFO: A-h0, B-h0, A-h1, B-h1 = 4 loads)
  STAGE_A(0, 0, 0); STAGE_B(0, 0, 0); STAGE_A(0, 1, 0); STAGE_B(0, 1, 0);

  const int nkt = K >> 6;
  for (int t = 0; t < nkt; ++t) {
    const int d = t & 1;
    const char* aB = ardb + d * 65536;
    const char* bB = brdb + d * 65536;
    const int kn = (t + 1) << 6;
    const bool pf = (t + 1) < nkt;
    bf16x8 a[4], b0, b1;
    // ---- P1: sync (A-h0,B-h0 landed), stage A-h0', compute (h0, n0/n1) ----
    SB0;
    asm volatile("s_waitcnt vmcnt(2)" ::: "memory");
    __builtin_amdgcn_s_barrier();
    asm volatile("" ::: "memory");
    SB0;
    if (pf) STAGE_A(d ^ 1, 0, kn);
#pragma unroll
    for (int m = 0; m < 4; m++) a[m] = *(const bf16x8*)(aB + m * 1024);
    b0 = *(const bf16x8*)(bB);
    b1 = *(const bf16x8*)(bB + 1024);
    __builtin_amdgcn_s_setprio(1);
#pragma unroll
    for (int m = 0; m < 4; m++) {
      acc[m][0] = mfma16(a[m], b0, acc[m][0]);
      acc[m][1] = mfma16(a[m], b1, acc[m][1]);
    }
    __builtin_amdgcn_s_setprio(0);
    // ---- P2: stage B-h0', compute (h0, n2/n3) ----
    if (pf) STAGE_B(d ^ 1, 0, kn);
    b0 = *(const bf16x8*)(bB + 2048);
    b1 = *(const bf16x8*)(bB + 3072);
    __builtin_amdgcn_s_setprio(1);
#pragma unroll
    for (int m = 0; m < 4; m++) {
      acc[m][2] = mfma16(a[m], b0, acc[m][2]);
      acc[m][3] = mfma16(a[m], b1, acc[m][3]);
    }
    __builtin_amdgcn_s_setprio(0);
    // ---- P3: sync (A-h1,B-h1 landed), stage A-h1', compute (h1, n0/n1) ----
    SB0;
    if (pf) asm volatile("s_waitcnt vmcnt(2)" ::: "memory");
    else    asm volatile("s_waitcnt vmcnt(0)" ::: "memory");
    __builtin_amdgcn_s_barrier();
    asm volatile("" ::: "memory");
    SB0;
    if (pf) STAGE_A(d ^ 1, 1, kn);
#pragma unroll
    for (int m = 0; m < 4; m++) a[m] = *(const bf16x8*)(aB + 16384 + m * 1024);
    b0 = *(const bf16x8*)(bB + 16384);
    b1 = *(const bf16x8*)(bB + 16384 + 1024);
    __builtin_amdgcn_s_setprio(1);
#pragma unroll
    for (int m = 0; m < 4; m++) {
      acc[m][0] = mfma16(a[m], b0, acc[m][0]);
      acc[m][1] = mfma16(a[m], b1, acc[m][1]);
    }
    __builtin_amdgcn_s_setprio(0);
    // ---- P4: stage B-h1', compute (h1, n2/n3) ----
    if (pf) STAGE_B(d ^ 1, 1, kn);
    b0 = *(const bf16x8*)(bB + 16384 + 2048);
    b1 = *(const bf16x8*)(bB + 16384 + 3072);
    __builtin_amdgcn_s_setprio(1);
#pragma unroll
    for (int m = 0; m < 4; m++) {
      acc[m][2] = mfma16(a[m], b0, acc[m][2]);
      acc[m][3] = mfma16(a[m], b1, acc[m][3]);
    }
    __builtin_amdgcn_s_setprio(0);
  }
#undef STAGE_A
#undef STAGE_B

  const int r4 = (lane >> 4) << 2;
  const size_t row0 = (size_t)mt * 256 + wr * 64;
  const int col0 = nt * 256 + wc * 64;
#pragma unroll
  for (int m = 0; m < 4; m++)
#pragma unroll
    for (int n = 0; n < 4; n++)
#pragma unroll
      for (int j = 0; j < 4; j++) {
        size_t row = row0 + m * 16 + r4 + j;
        size_t col = (size_t)col0 + n * 16 + l15;
        if (OUT_BF16) ((bf16*)Cp)[row * ldc + col] = __float2bfloat16(acc[m][n][j]);
        else          ((float*)Cp)[row * ldc + col] = acc[m][n][j];
      }
}

// ---------------- generic bf16 GEMM (128² m97-style) — small W2T prep ----------------
template <int OUT_BF16>
__global__ __launch_bounds__(256) void gemm_bt(
    const bf16* __restrict__ A, int lda,
    const bf16* __restrict__ Bt, int ldb,
    void* __restrict__ Cp, int ldc, int K, int ntiles) {
  __shared__ bf16 As[128 * 32];
  __shared__ bf16 Bs[128 * 32];
  const int tid = threadIdx.x;
  const int wave = tid >> 6, lane = tid & 63;
  const int wgid = (blockIdx.x & 7) * (gridDim.x >> 3) + (blockIdx.x >> 3);
  const int mt = wgid / ntiles, nt = wgid % ntiles;
  const int srow = tid >> 2, scol = (tid & 3) << 3;
  const bf16* ag = A + (size_t)(mt * 128 + srow) * lda + scol;
  const bf16* bg = Bt + (size_t)(nt * 128 + srow) * ldb + scol;
  char* asw = (char*)As + wave * 1024;
  char* bsw = (char*)Bs + wave * 1024;
  const int l15 = lane & 15, lk = (lane >> 4) << 3;
  const int wm = (wave >> 1) * 64, wn = (wave & 1) * 64;
  f32x4 acc[4][4] = {};
  for (int kt = 0; kt < K; kt += 32) {
    __syncthreads();
    async16(ag + kt, asw);
    async16(ag + kt + (size_t)64 * lda, asw + 4096);
    async16(bg + kt, bsw);
    async16(bg + kt + (size_t)64 * ldb, bsw + 4096);
    __syncthreads();
    bf16x8 af[4], bfr[4];
#pragma unroll
    for (int m = 0; m < 4; m++)
      af[m] = *(const bf16x8*)((const char*)As + (size_t)((wm + m * 16 + l15) * 32 + lk) * 2);
#pragma unroll
    for (int n = 0; n < 4; n++)
      bfr[n] = *(const bf16x8*)((const char*)Bs + (size_t)((wn + n * 16 + l15) * 32 + lk) * 2);
#pragma unroll
    for (int m = 0; m < 4; m++)
#pragma unroll
      for (int n = 0; n < 4; n++)
        acc[m][n] = mfma16(af[m], bfr[n], acc[m][n]);
  }
  const int r4 = (lane >> 4) << 2;
#pragma unroll
  for (int m = 0; m < 4; m++)
#pragma unroll
    for (int n = 0; n < 4; n++)
#pragma unroll
      for (int j = 0; j < 4; j++) {
        size_t row = (size_t)mt * 128 + wm + m * 16 + r4 + j;
        size_t col = (size_t)nt * 128 + wn + n * 16 + l15;
        if (OUT_BF16) ((bf16*)Cp)[row * ldc + col] = __float2bfloat16(acc[m][n][j]);
        else          ((float*)Cp)[row * ldc + col] = acc[m][n][j];
      }
}

// ---------------- compression: softmax over M + weighted sum, LN; writes K and V^T ----------------
__global__ __launch_bounds__(512) void compress_k(
    const bf16* __restrict__ cz, int ldcz, const float* __restrict__ b_comp,
    const float* __restrict__ gamma, const float* __restrict__ beta,
    bf16* __restrict__ k_comp, bf16* __restrict__ vt) {
  const int blk = blockIdx.x;
  const int t = threadIdx.x, c = t & 127, qtr = t >> 7;
  const size_t t0 = (size_t)blk * 128;
  float num = 0.f, den = 0.f;
  for (int m = qtr * 32; m < qtr * 32 + 32; m++) {
    const bf16* r = cz + (t0 + m) * ldcz;
    float w = expf(__bfloat162float(r[128 + c]) + b_comp[m * 128 + c]);
    den += w;
    num += w * __bfloat162float(r[c]);
  }
  __shared__ float sn[4][128], sd[4][128], sv[128];
  sn[qtr][c] = num;
  sd[qtr][c] = den;
  __syncthreads();
  if (qtr == 0)
    sv[c] = (sn[0][c] + sn[1][c] + sn[2][c] + sn[3][c]) /
            (sd[0][c] + sd[1][c] + sd[2][c] + sd[3][c]);
  __syncthreads();
  if (qtr == 0) {
    float v = sv[c];
    float mu = 0.f;
    for (int i = 0; i < 128; i++) mu += sv[i];
    mu *= (1.f / 128.f);
    float var = 0.f;
    for (int i = 0; i < 128; i++) { float d = sv[i] - mu; var += d * d; }
    var *= (1.f / 128.f);
    float kc = (v - mu) * rsqrtf(var + 1e-6f) * gamma[c] + beta[c];
    const int b = blk >> 6, kb = blk & 63;
    k_comp[(size_t)blk * 128 + c] = __float2bfloat16(kc);
    vt[(size_t)b * 8192 + c * 64 + kb] = __float2bfloat16(v);
  }
}

// ---------------- attention: fused q-LN+RoPE, K/V^T direct from global, swizzled LDS ----------------
__global__ __launch_bounds__(256) void attn_k(
    const bf16* __restrict__ qln, const bf16* __restrict__ kc,
    const bf16* __restrict__ vt, const float* __restrict__ sink_logits,
    const float* __restrict__ gamma, const float* __restrict__ beta,
    const float2* __restrict__ rope, bf16* __restrict__ out) {
  __shared__ bf16 Qs[128 * 128];  // swizzled rows; P[128][64] overlays after QK^T
  const int qt = blockIdx.x, hh = blockIdx.y, b = blockIdx.z;
  const int nk = qt + 1;
  const int ntk = (nk + 15) >> 4;
  const int nkk = (nk + 31) >> 5;
  const int tid = threadIdx.x, wave = tid >> 6, lane = tid & 63;
  const int l15 = lane & 15, g = lane >> 4;
  const size_t t0 = (size_t)b * 8192 + (size_t)qt * 128;
  const bf16* kbase = kc + (size_t)b * 64 * 128;
  const bf16* vbase = vt + (size_t)b * 128 * 64;

  {
    const int q = tid >> 1, hf = tid & 1;
    const bf16* gq = qln + (t0 + q) * 2048 + hh * 128 + hf * 64;
    bf16x8 r[8];
#pragma unroll
    for (int i = 0; i < 8; i++) r[i] = *(const bf16x8*)(gq + i * 8);
    float sum = 0.f;
#pragma unroll
    for (int i = 0; i < 8; i++)
#pragma unroll
      for (int j = 0; j < 8; j++) sum += b2f(r[i][j]);
    sum += __shfl_xor(sum, 1);
    const float mu = sum * (1.f / 128.f);
    float var = 0.f;
#pragma unroll
    for (int i = 0; i < 8; i++)
#pragma unroll
      for (int j = 0; j < 8; j++) { float d = b2f(r[i][j]) - mu; var += d * d; }
    var += __shfl_xor(var, 1);
    const float inv = rsqrtf(var * (1.f / 128.f) + 1e-6f);
    const int c0 = hf * 64;
#pragma unroll
    for (int i = 0; i < 8; i++) {
      float y[8];
#pragma unroll
      for (int j = 0; j < 8; j++) {
        int ch = c0 + i * 8 + j;
        y[j] = (b2f(r[i][j]) - mu) * inv * gamma[ch] + beta[ch];
      }
      if (hf) {
#pragma unroll
        for (int j = 0; j < 8; j += 2) {
          float2 cs = rope[((size_t)qt * 128 + q) * 32 + i * 4 + (j >> 1)];
          float e = y[j], o = y[j + 1];
          y[j] = e * cs.x - o * cs.y;
          y[j + 1] = e * cs.y + o * cs.x;
        }
      }
      bf16x8 w;
#pragma unroll
      for (int j = 0; j < 8; j++) w[j] = f2bs(y[j]);
      *(bf16x8*)(Qs + q * 128 + ((hf * 8 + (i ^ (q & 7))) << 3)) = w;
    }
  }
  __syncthreads();

  bf16x8 af[2][4];
#pragma unroll
  for (int m = 0; m < 2; m++) {
    const int q = wave * 32 + m * 16 + l15;
#pragma unroll
    for (int kk = 0; kk < 4; kk++) {
      const int u = (kk * 4 + g) ^ (q & 7);
      af[m][kk] = *(const bf16x8*)(Qs + q * 128 + u * 8);
    }
  }
  __syncthreads();  // Qs dead; safe to overlay P

  f32x4 sacc[2][4] = {};
#pragma unroll
  for (int n = 0; n < 4; n++) {
    if (n < ntk) {
      const bf16* kr = kbase + (n * 16 + l15) * 128 + g * 8;
      bf16x8 b0 = *(const bf16x8*)(kr);
      bf16x8 b1 = *(const bf16x8*)(kr + 32);
      bf16x8 b2 = *(const bf16x8*)(kr + 64);
      bf16x8 b3 = *(const bf16x8*)(kr + 96);
      __builtin_amdgcn_s_setprio(1);
      sacc[0][n] = mfma16(af[0][0], b0, sacc[0][n]);
      sacc[1][n] = mfma16(af[1][0], b0, sacc[1][n]);
      sacc[0][n] = mfma16(af[0][1], b1, sacc[0][n]);
      sacc[1][n] = mfma16(af[1][1], b1, sacc[1][n]);
      sacc[0][n] = mfma16(af[0][2], b2, sacc[0][n]);
      sacc[1][n] = mfma16(af[1][2], b2, sacc[1][n]);
      sacc[0][n] = mfma16(af[0][3], b3, sacc[0][n]);
      sacc[1][n] = mfma16(af[1][3], b3, sacc[1][n]);
      __builtin_amdgcn_s_setprio(0);
    }
  }

  const float sink = expf(sink_logits[hh]);
  const float scale = 0.088388347648318447f;  // 1/sqrt(128)
  bf16* P = Qs;
#pragma unroll
  for (int m = 0; m < 2; m++) {
    float pv[4][4];
    float rs[4] = {0.f, 0.f, 0.f, 0.f};
#pragma unroll
    for (int n = 0; n < 4; n++) {
      int key = n * 16 + l15;
#pragma unroll
      for (int j = 0; j < 4; j++) {
        float p = (key < nk) ? expf(sacc[m][n][j] * scale) : 0.f;
        pv[n][j] = p;
        rs[j] += p;
      }
    }
#pragma unroll
    for (int j = 0; j < 4; j++) {
      float v = rs[j];
      v += __shfl_xor(v, 1); v += __shfl_xor(v, 2);
      v += __shfl_xor(v, 4); v += __shfl_xor(v, 8);
      rs[j] = 1.0f / (v + sink);
    }
    const int row0 = wave * 32 + m * 16 + (g << 2);
#pragma unroll
    for (int n = 0; n < 4; n++)
#pragma unroll
      for (int j = 0; j < 4; j++) {
        int q = row0 + j;
        int k = n * 16 + l15;
        P[q * 64 + ((((k >> 3) ^ (q & 7)) << 3) | (k & 7))] =
            __float2bfloat16(pv[n][j] * rs[j]);
      }
  }
  // no barrier: PV reads only this wave's own P rows

  f32x4 oacc[2][8] = {};
#pragma unroll
  for (int kk = 0; kk < 2; kk++) {
    if (kk < nkk) {
      bf16x8 pa[2];
#pragma unroll
      for (int m = 0; m < 2; m++) {
        const int q = wave * 32 + m * 16 + l15;
        const int u = (kk * 4 + g) ^ (q & 7);
        pa[m] = *(const bf16x8*)(P + q * 64 + u * 8);
      }
#pragma unroll
      for (int n = 0; n < 8; n++) {
        bf16x8 vb = *(const bf16x8*)(vbase + (n * 16 + l15) * 64 + kk * 32 + g * 8);
        __builtin_amdgcn_s_setprio(1);
        oacc[0][n] = mfma16(pa[0], vb, oacc[0][n]);
        oacc[1][n] = mfma16(pa[1], vb, oacc[1][n]);
        __builtin_amdgcn_s_setprio(0);
      }
    }
  }

  bf16* ob = out + t0 * 2048 + hh * 128;
  const int r4 = g << 2;
#pragma unroll
  for (int m = 0; m < 2; m++)
#pragma unroll
    for (int n = 0; n < 8; n++)
#pragma unroll
      for (int j = 0; j < 4; j++)
        ob[(size_t)(wave * 32 + m * 16 + r4 + j) * 2048 + n * 16 + l15] =
            __float2bfloat16(oacc[m][n][j]);
}

extern "C" void kernel_launch(void* const* d_in, const int* in_sizes, int n_in,
                              void* d_out, int out_size, void* d_ws, size_t ws_size,
                              hipStream_t stream) {
  const float* x      = (const float*)d_in[0];
  const float* w_kv   = (const float*)d_in[1];
  const float* w_z    = (const float*)d_in[2];
  const float* b_comp = (const float*)d_in[3];
  const float* w_dq   = (const float*)d_in[4];
  const float* w_uq   = (const float*)d_in[5];
  const float* o_down = (const float*)d_in[6];
  const float* o_up   = (const float*)d_in[7];
  const float* kv_g   = (const float*)d_in[8];
  const float* kv_b   = (const float*)d_in[9];
  const float* q_g    = (const float*)d_in[10];
  const float* q_b    = (const float*)d_in[11];
  const float* sinkl  = (const float*)d_in[12];
  char* ws = (char*)d_ws;
  bf16*   WCZQ  = (bf16*)(ws + OFF_WCZQ);
  bf16*   WUQ   = (bf16*)(ws + OFF_WUQ);
  bf16*   DOWNB = (bf16*)(ws + OFF_DOWNB);
  bf16*   WUP   = (bf16*)(ws + OFF_WUP);
  bf16*   W2T   = (bf16*)(ws + OFF_W2T);
  bf16*   KC    = (bf16*)(ws + OFF_KC);
  bf16*   VT    = (bf16*)(ws + OFF_VT);
  float2* ROPE  = (float2*)(ws + OFF_ROPE);
  bf16*   XB    = (bf16*)(ws + OFF_XB);
  bf16*   CZQ   = (bf16*)(ws + OFF_CZQ);
  bf16*   QF    = (bf16*)(ws + OFF_QF);
  bf16*   ATT   = (bf16*)(ws + OFF_XB);
  float*  OUT   = (float*)d_out;

  // weight prep
  transpose_f32_bf16<<<dim3(4, 64), 256, 0, stream>>>(w_kv, WCZQ, 2048, 128);
  transpose_f32_bf16<<<dim3(4, 64), 256, 0, stream>>>(w_z, WCZQ + 128 * 2048, 2048, 128);
  transpose_f32_bf16<<<dim3(16, 64), 256, 0, stream>>>(w_dq, WCZQ + 256 * 2048, 2048, 512);
  transpose_f32_bf16<<<dim3(64, 16), 256, 0, stream>>>(w_uq, WUQ, 512, 2048);
  transpose_f32_bf16<<<dim3(64, 64), 256, 0, stream>>>(o_up, WUP, 2048, 2048);
  cvt_bf16_k<<<512, 256, 0, stream>>>(o_down, DOWNB);
  cvt_bf16_k<<<16384, 256, 0, stream>>>(x, XB);
  rope_table_k<<<1024, 256, 0, stream>>>(ROPE);
  // fused [c_proj | z | q_mid] = x @ [w_kv | w_z | w_dq]   (16384 x 768)
  gemm8p<1><<<192, 1024, 0, stream>>>(XB, DM, WCZQ, DM, CZQ, 768, DM, 3);
  // compression + kv LN (writes K row-major and V^T)
  compress_k<<<128, 512, 0, stream>>>(CZQ, 768, b_comp, kv_g, kv_b, KC, VT);
  // q = q_mid @ w_uq   (16384 x 2048, K=512)
  gemm8p<1><<<512, 1024, 0, stream>>>(CZQ + 256, 768, WUQ, 512, QF, DM, 512, 8);
  // attention (fused q-LN + rope)
  attn_k<<<dim3(64, 16, 2), 256, 0, stream>>>(QF, KC, VT, sinkl, q_g, q_b, ROPE, ATT);
  // W2T = up^T @ down (per group)
  for (int g = 0; g < 4; g++)
    gemm_bt<1><<<64, 256, 0, stream>>>(WUP + g * 512, DM, DOWNB + (size_t)g * 512 * 512, 512,
                                       W2T + g * 512, DM, 512, 4);
  // final: OUT = ATT @ W2T^T  (16384 x 2048, K=2048)
  gemm8p<0><<<512, 1024, 0, stream>>>(ATT, DM, W2T, DM, OUT, DM, DM, 8);
}

// Round 11
// 377.595 us; speedup vs baseline: 1.2009x; 1.1795x over previous
//
#include <hip/hip_runtime.h>
#include <hip/hip_bf16.h>

using bf16 = __hip_bfloat16;
typedef __attribute__((ext_vector_type(8))) short bf16x8;
typedef __attribute__((ext_vector_type(4))) float f32x4;

#define DM 2048

// ---- workspace offsets (bytes) ----
#define OFF_WCZQ  0x00000000ULL  // 768x2048 bf16 (w_kv^T | w_z^T | w_dq^T)
#define OFF_WUQ   0x00300000ULL  // 2048x512 bf16
#define OFF_DOWNB 0x00500000ULL  // 4x512x512 bf16 (o_down, plain cvt)
#define OFF_WUP   0x00700000ULL  // 2048x2048 bf16 (o_up^T)
#define OFF_W2T   0x00F00000ULL  // 2048x2048 bf16 (fused down*up, transposed)
#define OFF_KC    0x01700000ULL  // 2*64*128 bf16
#define OFF_VT    0x01710000ULL  // 2*128*64 bf16 (V transposed per batch)
#define OFF_ROPE  0x01720000ULL  // 8192*32 float2
#define OFF_XB    0x01A00000ULL  // 16384x2048 bf16 (x), reused for attn-out
#define OFF_CZQ   0x05A00000ULL  // 16384x768 bf16 (c_proj | z | q_mid)
#define OFF_QF    0x07300000ULL  // 16384x2048 bf16

__device__ __forceinline__ void async16(const void* g, void* l) {
  __builtin_amdgcn_global_load_lds(
      (const __attribute__((address_space(1))) unsigned int*)g,
      (__attribute__((address_space(3))) unsigned int*)l, 16, 0, 0);
}

__device__ __forceinline__ f32x4 mfma16(bf16x8 a, bf16x8 b, f32x4 c) {
  return __builtin_amdgcn_mfma_f32_16x16x32_bf16(a, b, c, 0, 0, 0);
}

__device__ __forceinline__ float b2f(short u) {
  unsigned x = ((unsigned)(unsigned short)u) << 16;
  return __builtin_bit_cast(float, x);
}
__device__ __forceinline__ short f2bs(float f) {
  return __builtin_bit_cast(short, __float2bfloat16(f));
}

#define SB0 __builtin_amdgcn_sched_barrier(0)

__device__ __forceinline__ void cvt8(const float* __restrict__ in, bf16* __restrict__ out, size_t i) {
  float4 a = *(const float4*)(in + i);
  float4 b = *(const float4*)(in + i + 4);
  struct alignas(16) B8 { bf16 v[8]; } r;
  r.v[0] = __float2bfloat16(a.x); r.v[1] = __float2bfloat16(a.y);
  r.v[2] = __float2bfloat16(a.z); r.v[3] = __float2bfloat16(a.w);
  r.v[4] = __float2bfloat16(b.x); r.v[5] = __float2bfloat16(b.y);
  r.v[6] = __float2bfloat16(b.z); r.v[7] = __float2bfloat16(b.w);
  *(B8*)(out + i) = r;
}

// ================= flat-grid prep: 6 transposes + o_down cvt + rope + x cvt =================
// block ranges: [0,256) w_kv T | [256,512) w_z T | [512,1536) w_dq T | [1536,2560) w_uq T |
// [2560,6656) o_up T | [6656,7168) o_down cvt | [7168,8192) rope | [8192,24576) x cvt
__global__ __launch_bounds__(256) void prep_k(
    const float* __restrict__ w_kv, const float* __restrict__ w_z,
    const float* __restrict__ w_dq, const float* __restrict__ w_uq,
    const float* __restrict__ o_up, const float* __restrict__ o_down,
    const float* __restrict__ x,
    bf16* __restrict__ WCZQ, bf16* __restrict__ WUQ, bf16* __restrict__ WUP,
    bf16* __restrict__ DOWNB, bf16* __restrict__ XB, float2* __restrict__ ROPE) {
  __shared__ float t[32][33];
  const int b = blockIdx.x;
  if (b < 6656) {
    const float* src; bf16* dst; int K, N, tx, ty;
    if (b < 256)       { src = w_kv; dst = WCZQ;              K = 2048; N = 128;  int i = b;        tx = i % 4;  ty = i / 4;  }
    else if (b < 512)  { src = w_z;  dst = WCZQ + 128 * 2048; K = 2048; N = 128;  int i = b - 256;  tx = i % 4;  ty = i / 4;  }
    else if (b < 1536) { src = w_dq; dst = WCZQ + 256 * 2048; K = 2048; N = 512;  int i = b - 512;  tx = i % 16; ty = i / 16; }
    else if (b < 2560) { src = w_uq; dst = WUQ;               K = 512;  N = 2048; int i = b - 1536; tx = i % 64; ty = i / 64; }
    else               { src = o_up; dst = WUP;               K = 2048; N = 2048; int i = b - 2560; tx = i % 64; ty = i / 64; }
    const int tn0 = tx * 32, tk0 = ty * 32;
    const int lx = threadIdx.x & 31, ly = threadIdx.x >> 5;
#pragma unroll
    for (int p = 0; p < 4; p++) {
      int k = tk0 + ly + p * 8, n = tn0 + lx;
      if (k < K && n < N) t[ly + p * 8][lx] = src[(size_t)k * N + n];
    }
    __syncthreads();
#pragma unroll
    for (int p = 0; p < 4; p++) {
      int n = tn0 + ly + p * 8, k = tk0 + lx;
      if (n < N && k < K) dst[(size_t)n * K + k] = __float2bfloat16(t[lx][ly + p * 8]);
    }
  } else if (b < 7168) {
    cvt8(o_down, DOWNB, ((size_t)(b - 6656) * 256 + threadIdx.x) * 8);
  } else if (b < 8192) {
    int idx = (b - 7168) * 256 + threadIdx.x;  // 8192*32 entries
    int s = idx >> 5, i = idx & 31;
    double f = pow(10000.0, -((double)(2 * i)) / 64.0);
    double a = (double)s * f;
    ROPE[idx] = make_float2((float)cos(a), (float)sin(a));
  } else {
    cvt8(x, XB, ((size_t)(b - 8192) * 256 + threadIdx.x) * 8);
  }
}

// ================= 256x256 8-phase GEMM: C = A(MxK,lda) @ Bt(NxK,ldb)^T =================
// 1024 thr / 16 waves (4Mx4N, 4 waves/SIMD for latency-hiding TLP); BK=64 as 2 k-halves;
// LDS [2dbuf][A,B][2kh][256][32] = 128 KiB. One async16 per thread covers a full 16 KB
// half-tile. Counted vmcnt(2) at the 2 sync points per K-tile; max 4 outstanding/wave.
// T2 bank swizzle: 16B unit u of row r stored at u^((r>>1)&3), via pre-swizzled global
// source (linear LDS dest) + swizzled read base. SYNC SKELETON = R3-stable; do not deepen.
template <int OUT_BF16>
__global__ __launch_bounds__(1024, 1) void gemm8p(
    const bf16* __restrict__ A, int lda,
    const bf16* __restrict__ Bt, int ldb,
    void* __restrict__ Cp, int ldc, int K, int ntiles) {
  __shared__ bf16 lds[2][2][2][256][32];  // 131072 B
  const int tid = threadIdx.x;
  const int lane = tid & 63, wid = tid >> 6;
  const int wr = wid >> 2, wc = wid & 3;  // 4x4 wave grid, 64x64 out per wave
  const int wgid = (blockIdx.x & 7) * (gridDim.x >> 3) + (blockIdx.x >> 3);
  const int mt = wgid / ntiles, nt = wgid % ntiles;
  const int srow = tid >> 2;                       // 0..255
  const int sunit = (tid & 3) ^ ((tid >> 3) & 3);  // source unit pre-swizzled
  const bf16* gA = A + (size_t)(mt * 256 + srow) * lda + (sunit << 3);
  const bf16* gB = Bt + (size_t)(nt * 256 + srow) * ldb + (sunit << 3);
  char* ldsA = (char*)lds + tid * 16;
  char* ldsB = (char*)lds + 32768 + tid * 16;

#define STAGE_A(dd, h, kc) async16(gA + (kc) + (h) * 32, ldsA + (dd) * 65536 + (h) * 16384)
#define STAGE_B(dd, h, kc) async16(gB + (kc) + (h) * 32, ldsB + (dd) * 65536 + (h) * 16384)

  const int l15 = lane & 15, g = lane >> 4;
  const int gsw = g ^ ((l15 >> 1) & 3);  // swizzled read unit
  const char* ardb = (char*)lds + (size_t)(wr * 64 + l15) * 64 + (gsw << 4);
  const char* brdb = (char*)lds + 32768 + (size_t)(wc * 64 + l15) * 64 + (gsw << 4);

  f32x4 acc[4][4] = {};
  // prologue: stage K-tile 0 (FIFO: A-h0, B-h0, A-h1, B-h1 = 4 loads)
  STAGE_A(0, 0, 0); STAGE_B(0, 0, 0); STAGE_A(0, 1, 0); STAGE_B(0, 1, 0);

  const int nkt = K >> 6;
  for (int t = 0; t < nkt; ++t) {
    const int d = t & 1;
    const char* aB = ardb + d * 65536;
    const char* bB = brdb + d * 65536;
    const int kn = (t + 1) << 6;
    const bool pf = (t + 1) < nkt;
    bf16x8 a[4], b0, b1;
    // ---- P1: sync (A-h0,B-h0 landed), stage A-h0', compute (h0, n0/n1) ----
    SB0;
    asm volatile("s_waitcnt vmcnt(2)" ::: "memory");
    __builtin_amdgcn_s_barrier();
    asm volatile("" ::: "memory");
    SB0;
    if (pf) STAGE_A(d ^ 1, 0, kn);
#pragma unroll
    for (int m = 0; m < 4; m++) a[m] = *(const bf16x8*)(aB + m * 1024);
    b0 = *(const bf16x8*)(bB);
    b1 = *(const bf16x8*)(bB + 1024);
    __builtin_amdgcn_s_setprio(1);
#pragma unroll
    for (int m = 0; m < 4; m++) {
      acc[m][0] = mfma16(a[m], b0, acc[m][0]);
      acc[m][1] = mfma16(a[m], b1, acc[m][1]);
    }
    __builtin_amdgcn_s_setprio(0);
    // ---- P2: stage B-h0', compute (h0, n2/n3) ----
    if (pf) STAGE_B(d ^ 1, 0, kn);
    b0 = *(const bf16x8*)(bB + 2048);
    b1 = *(const bf16x8*)(bB + 3072);
    __builtin_amdgcn_s_setprio(1);
#pragma unroll
    for (int m = 0; m < 4; m++) {
      acc[m][2] = mfma16(a[m], b0, acc[m][2]);
      acc[m][3] = mfma16(a[m], b1, acc[m][3]);
    }
    __builtin_amdgcn_s_setprio(0);
    // ---- P3: sync (A-h1,B-h1 landed), stage A-h1', compute (h1, n0/n1) ----
    SB0;
    if (pf) asm volatile("s_waitcnt vmcnt(2)" ::: "memory");
    else    asm volatile("s_waitcnt vmcnt(0)" ::: "memory");
    __builtin_amdgcn_s_barrier();
    asm volatile("" ::: "memory");
    SB0;
    if (pf) STAGE_A(d ^ 1, 1, kn);
#pragma unroll
    for (int m = 0; m < 4; m++) a[m] = *(const bf16x8*)(aB + 16384 + m * 1024);
    b0 = *(const bf16x8*)(bB + 16384);
    b1 = *(const bf16x8*)(bB + 16384 + 1024);
    __builtin_amdgcn_s_setprio(1);
#pragma unroll
    for (int m = 0; m < 4; m++) {
      acc[m][0] = mfma16(a[m], b0, acc[m][0]);
      acc[m][1] = mfma16(a[m], b1, acc[m][1]);
    }
    __builtin_amdgcn_s_setprio(0);
    // ---- P4: stage B-h1', compute (h1, n2/n3) ----
    if (pf) STAGE_B(d ^ 1, 1, kn);
    b0 = *(const bf16x8*)(bB + 16384 + 2048);
    b1 = *(const bf16x8*)(bB + 16384 + 3072);
    __builtin_amdgcn_s_setprio(1);
#pragma unroll
    for (int m = 0; m < 4; m++) {
      acc[m][2] = mfma16(a[m], b0, acc[m][2]);
      acc[m][3] = mfma16(a[m], b1, acc[m][3]);
    }
    __builtin_amdgcn_s_setprio(0);
  }
#undef STAGE_A
#undef STAGE_B

  const int r4 = (lane >> 4) << 2;
  const size_t row0 = (size_t)mt * 256 + wr * 64;
  const int col0 = nt * 256 + wc * 64;
#pragma unroll
  for (int m = 0; m < 4; m++)
#pragma unroll
    for (int n = 0; n < 4; n++)
#pragma unroll
      for (int j = 0; j < 4; j++) {
        size_t row = row0 + m * 16 + r4 + j;
        size_t col = (size_t)col0 + n * 16 + l15;
        if (OUT_BF16) ((bf16*)Cp)[row * ldc + col] = __float2bfloat16(acc[m][n][j]);
        else          ((float*)Cp)[row * ldc + col] = acc[m][n][j];
      }
}

// ---------------- batched W2T GEMM: 4 groups in one launch (grid 256, 64 blocks/group) ----------------
// W2T[o][g*512+i] = sum_j o_up[g*512+j][o] * o_down[g][i][j]; M=2048, N=512, K=512 per group.
__global__ __launch_bounds__(256) void gemm_w2t(
    const bf16* __restrict__ WUP, const bf16* __restrict__ DOWNB, bf16* __restrict__ W2T) {
  __shared__ bf16 As[128 * 32];
  __shared__ bf16 Bs[128 * 32];
  const int grp = blockIdx.x >> 6;
  const int inner = blockIdx.x & 63;
  const bf16* A = WUP + grp * 512;                       // lda = DM
  const bf16* Bt = DOWNB + (size_t)grp * 512 * 512;      // ldb = 512
  bf16* Cb = W2T + grp * 512;                            // ldc = DM
  const int tid = threadIdx.x;
  const int wave = tid >> 6, lane = tid & 63;
  const int wgid = (inner & 7) * 8 + (inner >> 3);
  const int mt = wgid >> 2, nt = wgid & 3;               // 16 x 4 tiles
  const int srow = tid >> 2, scol = (tid & 3) << 3;
  const bf16* ag = A + (size_t)(mt * 128 + srow) * DM + scol;
  const bf16* bg = Bt + (size_t)(nt * 128 + srow) * 512 + scol;
  char* asw = (char*)As + wave * 1024;
  char* bsw = (char*)Bs + wave * 1024;
  const int l15 = lane & 15, lk = (lane >> 4) << 3;
  const int wm = (wave >> 1) * 64, wn = (wave & 1) * 64;
  f32x4 acc[4][4] = {};
  for (int kt = 0; kt < 512; kt += 32) {
    __syncthreads();
    async16(ag + kt, asw);
    async16(ag + kt + (size_t)64 * DM, asw + 4096);
    async16(bg + kt, bsw);
    async16(bg + kt + (size_t)64 * 512, bsw + 4096);
    __syncthreads();
    bf16x8 af[4], bfr[4];
#pragma unroll
    for (int m = 0; m < 4; m++)
      af[m] = *(const bf16x8*)((const char*)As + (size_t)((wm + m * 16 + l15) * 32 + lk) * 2);
#pragma unroll
    for (int n = 0; n < 4; n++)
      bfr[n] = *(const bf16x8*)((const char*)Bs + (size_t)((wn + n * 16 + l15) * 32 + lk) * 2);
#pragma unroll
    for (int m = 0; m < 4; m++)
#pragma unroll
      for (int n = 0; n < 4; n++)
        acc[m][n] = mfma16(af[m], bfr[n], acc[m][n]);
  }
  const int r4 = (lane >> 4) << 2;
#pragma unroll
  for (int m = 0; m < 4; m++)
#pragma unroll
    for (int n = 0; n < 4; n++)
#pragma unroll
      for (int j = 0; j < 4; j++) {
        size_t row = (size_t)mt * 128 + wm + m * 16 + r4 + j;
        size_t col = (size_t)nt * 128 + wn + n * 16 + l15;
        Cb[row * DM + col] = __float2bfloat16(acc[m][n][j]);
      }
}

// ---------------- compression: softmax over M + weighted sum, LN; writes K and V^T ----------------
__global__ __launch_bounds__(512) void compress_k(
    const bf16* __restrict__ cz, int ldcz, const float* __restrict__ b_comp,
    const float* __restrict__ gamma, const float* __restrict__ beta,
    bf16* __restrict__ k_comp, bf16* __restrict__ vt) {
  const int blk = blockIdx.x;
  const int t = threadIdx.x, c = t & 127, qtr = t >> 7;
  const size_t t0 = (size_t)blk * 128;
  float num = 0.f, den = 0.f;
  for (int m = qtr * 32; m < qtr * 32 + 32; m++) {
    const bf16* r = cz + (t0 + m) * ldcz;
    float w = expf(__bfloat162float(r[128 + c]) + b_comp[m * 128 + c]);
    den += w;
    num += w * __bfloat162float(r[c]);
  }
  __shared__ float sn[4][128], sd[4][128], sv[128];
  sn[qtr][c] = num;
  sd[qtr][c] = den;
  __syncthreads();
  if (qtr == 0)
    sv[c] = (sn[0][c] + sn[1][c] + sn[2][c] + sn[3][c]) /
            (sd[0][c] + sd[1][c] + sd[2][c] + sd[3][c]);
  __syncthreads();
  if (qtr == 0) {
    float v = sv[c];
    float mu = 0.f;
    for (int i = 0; i < 128; i++) mu += sv[i];
    mu *= (1.f / 128.f);
    float var = 0.f;
    for (int i = 0; i < 128; i++) { float d = sv[i] - mu; var += d * d; }
    var *= (1.f / 128.f);
    float kc = (v - mu) * rsqrtf(var + 1e-6f) * gamma[c] + beta[c];
    const int b = blk >> 6, kb = blk & 63;
    k_comp[(size_t)blk * 128 + c] = __float2bfloat16(kc);
    vt[(size_t)b * 8192 + c * 64 + kb] = __float2bfloat16(v);
  }
}

// ---------------- attention: fused q-LN+RoPE, K/V^T direct from global, swizzled LDS ----------------
__global__ __launch_bounds__(256) void attn_k(
    const bf16* __restrict__ qln, const bf16* __restrict__ kc,
    const bf16* __restrict__ vt, const float* __restrict__ sink_logits,
    const float* __restrict__ gamma, const float* __restrict__ beta,
    const float2* __restrict__ rope, bf16* __restrict__ out) {
  __shared__ bf16 Qs[128 * 128];  // swizzled rows; P[128][64] overlays after QK^T
  const int qt = blockIdx.x, hh = blockIdx.y, b = blockIdx.z;
  const int nk = qt + 1;
  const int ntk = (nk + 15) >> 4;
  const int nkk = (nk + 31) >> 5;
  const int tid = threadIdx.x, wave = tid >> 6, lane = tid & 63;
  const int l15 = lane & 15, g = lane >> 4;
  const size_t t0 = (size_t)b * 8192 + (size_t)qt * 128;
  const bf16* kbase = kc + (size_t)b * 64 * 128;
  const bf16* vbase = vt + (size_t)b * 128 * 64;

  {
    const int q = tid >> 1, hf = tid & 1;
    const bf16* gq = qln + (t0 + q) * 2048 + hh * 128 + hf * 64;
    bf16x8 r[8];
#pragma unroll
    for (int i = 0; i < 8; i++) r[i] = *(const bf16x8*)(gq + i * 8);
    float sum = 0.f;
#pragma unroll
    for (int i = 0; i < 8; i++)
#pragma unroll
      for (int j = 0; j < 8; j++) sum += b2f(r[i][j]);
    sum += __shfl_xor(sum, 1);
    const float mu = sum * (1.f / 128.f);
    float var = 0.f;
#pragma unroll
    for (int i = 0; i < 8; i++)
#pragma unroll
      for (int j = 0; j < 8; j++) { float d = b2f(r[i][j]) - mu; var += d * d; }
    var += __shfl_xor(var, 1);
    const float inv = rsqrtf(var * (1.f / 128.f) + 1e-6f);
    const int c0 = hf * 64;
#pragma unroll
    for (int i = 0; i < 8; i++) {
      float y[8];
#pragma unroll
      for (int j = 0; j < 8; j++) {
        int ch = c0 + i * 8 + j;
        y[j] = (b2f(r[i][j]) - mu) * inv * gamma[ch] + beta[ch];
      }
      if (hf) {
#pragma unroll
        for (int j = 0; j < 8; j += 2) {
          float2 cs = rope[((size_t)qt * 128 + q) * 32 + i * 4 + (j >> 1)];
          float e = y[j], o = y[j + 1];
          y[j] = e * cs.x - o * cs.y;
          y[j + 1] = e * cs.y + o * cs.x;
        }
      }
      bf16x8 w;
#pragma unroll
      for (int j = 0; j < 8; j++) w[j] = f2bs(y[j]);
      *(bf16x8*)(Qs + q * 128 + ((hf * 8 + (i ^ (q & 7))) << 3)) = w;
    }
  }
  __syncthreads();

  bf16x8 af[2][4];
#pragma unroll
  for (int m = 0; m < 2; m++) {
    const int q = wave * 32 + m * 16 + l15;
#pragma unroll
    for (int kk = 0; kk < 4; kk++) {
      const int u = (kk * 4 + g) ^ (q & 7);
      af[m][kk] = *(const bf16x8*)(Qs + q * 128 + u * 8);
    }
  }
  __syncthreads();  // Qs dead; safe to overlay P

  f32x4 sacc[2][4] = {};
#pragma unroll
  for (int n = 0; n < 4; n++) {
    if (n < ntk) {
      const bf16* kr = kbase + (n * 16 + l15) * 128 + g * 8;
      bf16x8 b0 = *(const bf16x8*)(kr);
      bf16x8 b1 = *(const bf16x8*)(kr + 32);
      bf16x8 b2 = *(const bf16x8*)(kr + 64);
      bf16x8 b3 = *(const bf16x8*)(kr + 96);
      __builtin_amdgcn_s_setprio(1);
      sacc[0][n] = mfma16(af[0][0], b0, sacc[0][n]);
      sacc[1][n] = mfma16(af[1][0], b0, sacc[1][n]);
      sacc[0][n] = mfma16(af[0][1], b1, sacc[0][n]);
      sacc[1][n] = mfma16(af[1][1], b1, sacc[1][n]);
      sacc[0][n] = mfma16(af[0][2], b2, sacc[0][n]);
      sacc[1][n] = mfma16(af[1][2], b2, sacc[1][n]);
      sacc[0][n] = mfma16(af[0][3], b3, sacc[0][n]);
      sacc[1][n] = mfma16(af[1][3], b3, sacc[1][n]);
      __builtin_amdgcn_s_setprio(0);
    }
  }

  const float sink = expf(sink_logits[hh]);
  const float scale = 0.088388347648318447f;  // 1/sqrt(128)
  bf16* P = Qs;
#pragma unroll
  for (int m = 0; m < 2; m++) {
    float pv[4][4];
    float rs[4] = {0.f, 0.f, 0.f, 0.f};
#pragma unroll
    for (int n = 0; n < 4; n++) {
      int key = n * 16 + l15;
#pragma unroll
      for (int j = 0; j < 4; j++) {
        float p = (key < nk) ? expf(sacc[m][n][j] * scale) : 0.f;
        pv[n][j] = p;
        rs[j] += p;
      }
    }
#pragma unroll
    for (int j = 0; j < 4; j++) {
      float v = rs[j];
      v += __shfl_xor(v, 1); v += __shfl_xor(v, 2);
      v += __shfl_xor(v, 4); v += __shfl_xor(v, 8);
      rs[j] = 1.0f / (v + sink);
    }
    const int row0 = wave * 32 + m * 16 + (g << 2);
#pragma unroll
    for (int n = 0; n < 4; n++)
#pragma unroll
      for (int j = 0; j < 4; j++) {
        int q = row0 + j;
        int k = n * 16 + l15;
        P[q * 64 + ((((k >> 3) ^ (q & 7)) << 3) | (k & 7))] =
            __float2bfloat16(pv[n][j] * rs[j]);
      }
  }
  // no barrier: PV reads only this wave's own P rows

  f32x4 oacc[2][8] = {};
#pragma unroll
  for (int kk = 0; kk < 2; kk++) {
    if (kk < nkk) {
      bf16x8 pa[2];
#pragma unroll
      for (int m = 0; m < 2; m++) {
        const int q = wave * 32 + m * 16 + l15;
        const int u = (kk * 4 + g) ^ (q & 7);
        pa[m] = *(const bf16x8*)(P + q * 64 + u * 8);
      }
#pragma unroll
      for (int n = 0; n < 8; n++) {
        bf16x8 vb = *(const bf16x8*)(vbase + (n * 16 + l15) * 64 + kk * 32 + g * 8);
        __builtin_amdgcn_s_setprio(1);
        oacc[0][n] = mfma16(pa[0], vb, oacc[0][n]);
        oacc[1][n] = mfma16(pa[1], vb, oacc[1][n]);
        __builtin_amdgcn_s_setprio(0);
      }
    }
  }

  bf16* ob = out + t0 * 2048 + hh * 128;
  const int r4 = g << 2;
#pragma unroll
  for (int m = 0; m < 2; m++)
#pragma unroll
    for (int n = 0; n < 8; n++)
#pragma unroll
      for (int j = 0; j < 4; j++)
        ob[(size_t)(wave * 32 + m * 16 + r4 + j) * 2048 + n * 16 + l15] =
            __float2bfloat16(oacc[m][n][j]);
}

extern "C" void kernel_launch(void* const* d_in, const int* in_sizes, int n_in,
                              void* d_out, int out_size, void* d_ws, size_t ws_size,
                              hipStream_t stream) {
  const float* x      = (const float*)d_in[0];
  const float* w_kv   = (const float*)d_in[1];
  const float* w_z    = (const float*)d_in[2];
  const float* b_comp = (const float*)d_in[3];
  const float* w_dq   = (const float*)d_in[4];
  const float* w_uq   = (const float*)d_in[5];
  const float* o_down = (const float*)d_in[6];
  const float* o_up   = (const float*)d_in[7];
  const float* kv_g   = (const float*)d_in[8];
  const float* kv_b   = (const float*)d_in[9];
  const float* q_g    = (const float*)d_in[10];
  const float* q_b    = (const float*)d_in[11];
  const float* sinkl  = (const float*)d_in[12];
  char* ws = (char*)d_ws;
  bf16*   WCZQ  = (bf16*)(ws + OFF_WCZQ);
  bf16*   WUQ   = (bf16*)(ws + OFF_WUQ);
  bf16*   DOWNB = (bf16*)(ws + OFF_DOWNB);
  bf16*   WUP   = (bf16*)(ws + OFF_WUP);
  bf16*   W2T   = (bf16*)(ws + OFF_W2T);
  bf16*   KC    = (bf16*)(ws + OFF_KC);
  bf16*   VT    = (bf16*)(ws + OFF_VT);
  float2* ROPE  = (float2*)(ws + OFF_ROPE);
  bf16*   XB    = (bf16*)(ws + OFF_XB);
  bf16*   CZQ   = (bf16*)(ws + OFF_CZQ);
  bf16*   QF    = (bf16*)(ws + OFF_QF);
  bf16*   ATT   = (bf16*)(ws + OFF_XB);
  float*  OUT   = (float*)d_out;

  // all weight prep + converts + rope table in one launch
  prep_k<<<24576, 256, 0, stream>>>(w_kv, w_z, w_dq, w_uq, o_up, o_down, x,
                                    WCZQ, WUQ, WUP, DOWNB, XB, ROPE);
  // W2T = up^T @ down (4 groups batched)
  gemm_w2t<<<256, 256, 0, stream>>>(WUP, DOWNB, W2T);
  // fused [c_proj | z | q_mid] = x @ [w_kv | w_z | w_dq]   (16384 x 768)
  gemm8p<1><<<192, 1024, 0, stream>>>(XB, DM, WCZQ, DM, CZQ, 768, DM, 3);
  // compression + kv LN (writes K row-major and V^T)
  compress_k<<<128, 512, 0, stream>>>(CZQ, 768, b_comp, kv_g, kv_b, KC, VT);
  // q = q_mid @ w_uq   (16384 x 2048, K=512)
  gemm8p<1><<<512, 1024, 0, stream>>>(CZQ + 256, 768, WUQ, 512, QF, DM, 512, 8);
  // attention (fused q-LN + rope)
  attn_k<<<dim3(64, 16, 2), 256, 0, stream>>>(QF, KC, VT, sinkl, q_g, q_b, ROPE, ATT);
  // final: OUT = ATT @ W2T^T  (16384 x 2048, K=2048)
  gemm8p<0><<<512, 1024, 0, stream>>>(ATT, DM, W2T, DM, OUT, DM, DM, 8);
}

// Round 12
// 361.911 us; speedup vs baseline: 1.2530x; 1.0433x over previous
//
#include <hip/hip_runtime.h>
#include <hip/hip_bf16.h>

using bf16 = __hip_bfloat16;
typedef __attribute__((ext_vector_type(8))) short bf16x8;
typedef __attribute__((ext_vector_type(4))) float f32x4;

#define DM 2048

// ---- workspace offsets (bytes) ----
#define OFF_WCZQ  0x00000000ULL  // 768x2048 bf16 (w_kv^T | w_z^T | w_dq^T)
#define OFF_WUQ   0x00300000ULL  // 2048x512 bf16
#define OFF_DOWNB 0x00500000ULL  // 4x512x512 bf16 (o_down, plain cvt)
#define OFF_WUP   0x00700000ULL  // 2048x2048 bf16 (o_up^T)
#define OFF_W2T   0x00F00000ULL  // 2048x2048 bf16 (fused down*up, transposed)
#define OFF_KC    0x01700000ULL  // 2*64*128 bf16
#define OFF_VT    0x01710000ULL  // 2*128*64 bf16 (V transposed per batch)
#define OFF_ROPE  0x01720000ULL  // 8192*32 float2
#define OFF_XB    0x01A00000ULL  // 16384x2048 bf16 (x), reused for attn-out
#define OFF_CZQ   0x05A00000ULL  // 16384x768 bf16 (c_proj | z | q_mid)
#define OFF_QF    0x07300000ULL  // 16384x2048 bf16

__device__ __forceinline__ void async16(const void* g, void* l) {
  __builtin_amdgcn_global_load_lds(
      (const __attribute__((address_space(1))) unsigned int*)g,
      (__attribute__((address_space(3))) unsigned int*)l, 16, 0, 0);
}

__device__ __forceinline__ f32x4 mfma16(bf16x8 a, bf16x8 b, f32x4 c) {
  return __builtin_amdgcn_mfma_f32_16x16x32_bf16(a, b, c, 0, 0, 0);
}

__device__ __forceinline__ float b2f(short u) {
  unsigned x = ((unsigned)(unsigned short)u) << 16;
  return __builtin_bit_cast(float, x);
}
__device__ __forceinline__ short f2bs(float f) {
  return __builtin_bit_cast(short, __float2bfloat16(f));
}

#define SB0 __builtin_amdgcn_sched_barrier(0)

__device__ __forceinline__ void cvt8(const float* __restrict__ in, bf16* __restrict__ out, size_t i) {
  float4 a = *(const float4*)(in + i);
  float4 b = *(const float4*)(in + i + 4);
  struct alignas(16) B8 { bf16 v[8]; } r;
  r.v[0] = __float2bfloat16(a.x); r.v[1] = __float2bfloat16(a.y);
  r.v[2] = __float2bfloat16(a.z); r.v[3] = __float2bfloat16(a.w);
  r.v[4] = __float2bfloat16(b.x); r.v[5] = __float2bfloat16(b.y);
  r.v[6] = __float2bfloat16(b.z); r.v[7] = __float2bfloat16(b.w);
  *(B8*)(out + i) = r;
}

// ================= flat-grid prep: 6 transposes + o_down cvt + rope + x cvt =================
__global__ __launch_bounds__(256) void prep_k(
    const float* __restrict__ w_kv, const float* __restrict__ w_z,
    const float* __restrict__ w_dq, const float* __restrict__ w_uq,
    const float* __restrict__ o_up, const float* __restrict__ o_down,
    const float* __restrict__ x,
    bf16* __restrict__ WCZQ, bf16* __restrict__ WUQ, bf16* __restrict__ WUP,
    bf16* __restrict__ DOWNB, bf16* __restrict__ XB, float2* __restrict__ ROPE) {
  __shared__ float t[32][33];
  const int b = blockIdx.x;
  if (b < 6656) {
    const float* src; bf16* dst; int K, N, tx, ty;
    if (b < 256)       { src = w_kv; dst = WCZQ;              K = 2048; N = 128;  int i = b;        tx = i % 4;  ty = i / 4;  }
    else if (b < 512)  { src = w_z;  dst = WCZQ + 128 * 2048; K = 2048; N = 128;  int i = b - 256;  tx = i % 4;  ty = i / 4;  }
    else if (b < 1536) { src = w_dq; dst = WCZQ + 256 * 2048; K = 2048; N = 512;  int i = b - 512;  tx = i % 16; ty = i / 16; }
    else if (b < 2560) { src = w_uq; dst = WUQ;               K = 512;  N = 2048; int i = b - 1536; tx = i % 64; ty = i / 64; }
    else               { src = o_up; dst = WUP;               K = 2048; N = 2048; int i = b - 2560; tx = i % 64; ty = i / 64; }
    const int tn0 = tx * 32, tk0 = ty * 32;
    const int lx = threadIdx.x & 31, ly = threadIdx.x >> 5;
#pragma unroll
    for (int p = 0; p < 4; p++) {
      int k = tk0 + ly + p * 8, n = tn0 + lx;
      if (k < K && n < N) t[ly + p * 8][lx] = src[(size_t)k * N + n];
    }
    __syncthreads();
#pragma unroll
    for (int p = 0; p < 4; p++) {
      int n = tn0 + ly + p * 8, k = tk0 + lx;
      if (n < N && k < K) dst[(size_t)n * K + k] = __float2bfloat16(t[lx][ly + p * 8]);
    }
  } else if (b < 7168) {
    cvt8(o_down, DOWNB, ((size_t)(b - 6656) * 256 + threadIdx.x) * 8);
  } else if (b < 8192) {
    int idx = (b - 7168) * 256 + threadIdx.x;  // 8192*32 entries
    int s = idx >> 5, i = idx & 31;
    double f = pow(10000.0, -((double)(2 * i)) / 64.0);
    double a = (double)s * f;
    ROPE[idx] = make_float2((float)cos(a), (float)sin(a));
  } else {
    cvt8(x, XB, ((size_t)(b - 8192) * 256 + threadIdx.x) * 8);
  }
}

// ================= 256x256 8-phase GEMM body: C = A(MxK,lda) @ Bt(NxK,ldb)^T =================
// 1024 thr / 16 waves (4Mx4N); BK=64 as 2 k-halves; LDS 128 KiB passed in.
// Counted vmcnt(2) at the 2 sync points per K-tile; max 4 outstanding/wave.
// T2 bank swizzle via pre-swizzled global source + swizzled read base.
// SYNC SKELETON = R3-stable; do not deepen (12-outstanding variants raced).
template <int OUT_BF16>
__device__ __forceinline__ void gemm8p_body(
    char* ldsb,
    const bf16* __restrict__ A, int lda,
    const bf16* __restrict__ Bt, int ldb,
    void* __restrict__ Cp, int ldc, int K, int ntiles, int wgid) {
  const int tid = threadIdx.x;
  const int lane = tid & 63, wid = tid >> 6;
  const int wr = wid >> 2, wc = wid & 3;  // 4x4 wave grid, 64x64 out per wave
  const int mt = wgid / ntiles, nt = wgid % ntiles;
  const int srow = tid >> 2;                       // 0..255
  const int sunit = (tid & 3) ^ ((tid >> 3) & 3);  // source unit pre-swizzled
  const bf16* gA = A + (size_t)(mt * 256 + srow) * lda + (sunit << 3);
  const bf16* gB = Bt + (size_t)(nt * 256 + srow) * ldb + (sunit << 3);
  char* ldsA = ldsb + tid * 16;
  char* ldsB = ldsb + 32768 + tid * 16;

#define STAGE_A(dd, h, kc) async16(gA + (kc) + (h) * 32, ldsA + (dd) * 65536 + (h) * 16384)
#define STAGE_B(dd, h, kc) async16(gB + (kc) + (h) * 32, ldsB + (dd) * 65536 + (h) * 16384)

  const int l15 = lane & 15, g = lane >> 4;
  const int gsw = g ^ ((l15 >> 1) & 3);  // swizzled read unit
  const char* ardb = ldsb + (size_t)(wr * 64 + l15) * 64 + (gsw << 4);
  const char* brdb = ldsb + 32768 + (size_t)(wc * 64 + l15) * 64 + (gsw << 4);

  f32x4 acc[4][4] = {};
  // prologue: stage K-tile 0 (FIFO: A-h0, B-h0, A-h1, B-h1 = 4 loads)
  STAGE_A(0, 0, 0); STAGE_B(0, 0, 0); STAGE_A(0, 1, 0); STAGE_B(0, 1, 0);

  const int nkt = K >> 6;
  for (int t = 0; t < nkt; ++t) {
    const int d = t & 1;
    const char* aB = ardb + d * 65536;
    const char* bB = brdb + d * 65536;
    const int kn = (t + 1) << 6;
    const bool pf = (t + 1) < nkt;
    bf16x8 a[4], b0, b1;
    // ---- P1: sync (A-h0,B-h0 landed), stage A-h0', compute (h0, n0/n1) ----
    SB0;
    asm volatile("s_waitcnt vmcnt(2)" ::: "memory");
    __builtin_amdgcn_s_barrier();
    asm volatile("" ::: "memory");
    SB0;
    if (pf) STAGE_A(d ^ 1, 0, kn);
#pragma unroll
    for (int m = 0; m < 4; m++) a[m] = *(const bf16x8*)(aB + m * 1024);
    b0 = *(const bf16x8*)(bB);
    b1 = *(const bf16x8*)(bB + 1024);
    __builtin_amdgcn_s_setprio(1);
#pragma unroll
    for (int m = 0; m < 4; m++) {
      acc[m][0] = mfma16(a[m], b0, acc[m][0]);
      acc[m][1] = mfma16(a[m], b1, acc[m][1]);
    }
    __builtin_amdgcn_s_setprio(0);
    // ---- P2: stage B-h0', compute (h0, n2/n3) ----
    if (pf) STAGE_B(d ^ 1, 0, kn);
    b0 = *(const bf16x8*)(bB + 2048);
    b1 = *(const bf16x8*)(bB + 3072);
    __builtin_amdgcn_s_setprio(1);
#pragma unroll
    for (int m = 0; m < 4; m++) {
      acc[m][2] = mfma16(a[m], b0, acc[m][2]);
      acc[m][3] = mfma16(a[m], b1, acc[m][3]);
    }
    __builtin_amdgcn_s_setprio(0);
    // ---- P3: sync (A-h1,B-h1 landed), stage A-h1', compute (h1, n0/n1) ----
    SB0;
    if (pf) asm volatile("s_waitcnt vmcnt(2)" ::: "memory");
    else    asm volatile("s_waitcnt vmcnt(0)" ::: "memory");
    __builtin_amdgcn_s_barrier();
    asm volatile("" ::: "memory");
    SB0;
    if (pf) STAGE_A(d ^ 1, 1, kn);
#pragma unroll
    for (int m = 0; m < 4; m++) a[m] = *(const bf16x8*)(aB + 16384 + m * 1024);
    b0 = *(const bf16x8*)(bB + 16384);
    b1 = *(const bf16x8*)(bB + 16384 + 1024);
    __builtin_amdgcn_s_setprio(1);
#pragma unroll
    for (int m = 0; m < 4; m++) {
      acc[m][0] = mfma16(a[m], b0, acc[m][0]);
      acc[m][1] = mfma16(a[m], b1, acc[m][1]);
    }
    __builtin_amdgcn_s_setprio(0);
    // ---- P4: stage B-h1', compute (h1, n2/n3) ----
    if (pf) STAGE_B(d ^ 1, 1, kn);
    b0 = *(const bf16x8*)(bB + 16384 + 2048);
    b1 = *(const bf16x8*)(bB + 16384 + 3072);
    __builtin_amdgcn_s_setprio(1);
#pragma unroll
    for (int m = 0; m < 4; m++) {
      acc[m][2] = mfma16(a[m], b0, acc[m][2]);
      acc[m][3] = mfma16(a[m], b1, acc[m][3]);
    }
    __builtin_amdgcn_s_setprio(0);
  }
#undef STAGE_A
#undef STAGE_B

  const int r4 = (lane >> 4) << 2;
  const size_t row0 = (size_t)mt * 256 + wr * 64;
  const int col0 = nt * 256 + wc * 64;
#pragma unroll
  for (int m = 0; m < 4; m++)
#pragma unroll
    for (int n = 0; n < 4; n++)
#pragma unroll
      for (int j = 0; j < 4; j++) {
        size_t row = row0 + m * 16 + r4 + j;
        size_t col = (size_t)col0 + n * 16 + l15;
        if (OUT_BF16) ((bf16*)Cp)[row * ldc + col] = __float2bfloat16(acc[m][n][j]);
        else          ((float*)Cp)[row * ldc + col] = acc[m][n][j];
      }
}

template <int OUT_BF16>
__global__ __launch_bounds__(1024, 1) void gemm8p(
    const bf16* __restrict__ A, int lda,
    const bf16* __restrict__ Bt, int ldb,
    void* __restrict__ Cp, int ldc, int K, int ntiles) {
  __shared__ __align__(16) char lds[131072];
  const int wgid = (blockIdx.x & 7) * (gridDim.x >> 3) + (blockIdx.x >> 3);
  gemm8p_body<OUT_BF16>(lds, A, lda, Bt, ldb, Cp, ldc, K, ntiles, wgid);
}

// ---------------- combined launch: czq GEMM (blocks 0..191) + W2T group GEMMs (192..255) ----------------
// Fills exactly 256 CUs; W2T (4 groups x M=2048,N=512,K=512 = 16 blocks each) rides along free.
__global__ __launch_bounds__(1024, 1) void czq_w2t_k(
    const bf16* __restrict__ XB, const bf16* __restrict__ WCZQ, bf16* __restrict__ CZQ,
    const bf16* __restrict__ WUP, const bf16* __restrict__ DOWNB, bf16* __restrict__ W2T) {
  __shared__ __align__(16) char lds[131072];
  const int bx = blockIdx.x;
  if (bx < 192) {
    const int wgid = (bx & 7) * 24 + (bx >> 3);  // bijective: 192 % 8 == 0
    gemm8p_body<1>(lds, XB, DM, WCZQ, DM, CZQ, 768, DM, 3, wgid);
  } else {
    const int b2 = bx - 192;
    const int grp = b2 >> 4, inner = b2 & 15;
    const int wgid = (inner & 7) * 2 + (inner >> 3);
    gemm8p_body<1>(lds, WUP + grp * 512, DM, DOWNB + (size_t)grp * 512 * 512, 512,
                   W2T + grp * 512, DM, 512, 2, wgid);
  }
}

// ---------------- compression: softmax over M + weighted sum, LN; writes K and V^T ----------------
__global__ __launch_bounds__(512) void compress_k(
    const bf16* __restrict__ cz, int ldcz, const float* __restrict__ b_comp,
    const float* __restrict__ gamma, const float* __restrict__ beta,
    bf16* __restrict__ k_comp, bf16* __restrict__ vt) {
  const int blk = blockIdx.x;
  const int t = threadIdx.x, c = t & 127, qtr = t >> 7;
  const size_t t0 = (size_t)blk * 128;
  float num = 0.f, den = 0.f;
  for (int m = qtr * 32; m < qtr * 32 + 32; m++) {
    const bf16* r = cz + (t0 + m) * ldcz;
    float w = expf(__bfloat162float(r[128 + c]) + b_comp[m * 128 + c]);
    den += w;
    num += w * __bfloat162float(r[c]);
  }
  __shared__ float sn[4][128], sd[4][128], sv[128];
  sn[qtr][c] = num;
  sd[qtr][c] = den;
  __syncthreads();
  if (qtr == 0)
    sv[c] = (sn[0][c] + sn[1][c] + sn[2][c] + sn[3][c]) /
            (sd[0][c] + sd[1][c] + sd[2][c] + sd[3][c]);
  __syncthreads();
  if (qtr == 0) {
    float v = sv[c];
    float mu = 0.f;
    for (int i = 0; i < 128; i++) mu += sv[i];
    mu *= (1.f / 128.f);
    float var = 0.f;
    for (int i = 0; i < 128; i++) { float d = sv[i] - mu; var += d * d; }
    var *= (1.f / 128.f);
    float kc = (v - mu) * rsqrtf(var + 1e-6f) * gamma[c] + beta[c];
    const int b = blk >> 6, kb = blk & 63;
    k_comp[(size_t)blk * 128 + c] = __float2bfloat16(kc);
    vt[(size_t)b * 8192 + c * 64 + kb] = __float2bfloat16(v);
  }
}

// ---------------- attention: fused q-LN+RoPE, K/V^T direct from global, swizzled LDS ----------------
__global__ __launch_bounds__(256) void attn_k(
    const bf16* __restrict__ qln, const bf16* __restrict__ kc,
    const bf16* __restrict__ vt, const float* __restrict__ sink_logits,
    const float* __restrict__ gamma, const float* __restrict__ beta,
    const float2* __restrict__ rope, bf16* __restrict__ out) {
  __shared__ bf16 Qs[128 * 128];  // swizzled rows; P[128][64] overlays after QK^T
  const int qt = blockIdx.x, hh = blockIdx.y, b = blockIdx.z;
  const int nk = qt + 1;
  const int ntk = (nk + 15) >> 4;
  const int nkk = (nk + 31) >> 5;
  const int tid = threadIdx.x, wave = tid >> 6, lane = tid & 63;
  const int l15 = lane & 15, g = lane >> 4;
  const size_t t0 = (size_t)b * 8192 + (size_t)qt * 128;
  const bf16* kbase = kc + (size_t)b * 64 * 128;
  const bf16* vbase = vt + (size_t)b * 128 * 64;

  {
    const int q = tid >> 1, hf = tid & 1;
    const bf16* gq = qln + (t0 + q) * 2048 + hh * 128 + hf * 64;
    bf16x8 r[8];
#pragma unroll
    for (int i = 0; i < 8; i++) r[i] = *(const bf16x8*)(gq + i * 8);
    float sum = 0.f;
#pragma unroll
    for (int i = 0; i < 8; i++)
#pragma unroll
      for (int j = 0; j < 8; j++) sum += b2f(r[i][j]);
    sum += __shfl_xor(sum, 1);
    const float mu = sum * (1.f / 128.f);
    float var = 0.f;
#pragma unroll
    for (int i = 0; i < 8; i++)
#pragma unroll
      for (int j = 0; j < 8; j++) { float d = b2f(r[i][j]) - mu; var += d * d; }
    var += __shfl_xor(var, 1);
    const float inv = rsqrtf(var * (1.f / 128.f) + 1e-6f);
    const int c0 = hf * 64;
#pragma unroll
    for (int i = 0; i < 8; i++) {
      float y[8];
#pragma unroll
      for (int j = 0; j < 8; j++) {
        int ch = c0 + i * 8 + j;
        y[j] = (b2f(r[i][j]) - mu) * inv * gamma[ch] + beta[ch];
      }
      if (hf) {
#pragma unroll
        for (int j = 0; j < 8; j += 2) {
          float2 cs = rope[((size_t)qt * 128 + q) * 32 + i * 4 + (j >> 1)];
          float e = y[j], o = y[j + 1];
          y[j] = e * cs.x - o * cs.y;
          y[j + 1] = e * cs.y + o * cs.x;
        }
      }
      bf16x8 w;
#pragma unroll
      for (int j = 0; j < 8; j++) w[j] = f2bs(y[j]);
      *(bf16x8*)(Qs + q * 128 + ((hf * 8 + (i ^ (q & 7))) << 3)) = w;
    }
  }
  __syncthreads();

  bf16x8 af[2][4];
#pragma unroll
  for (int m = 0; m < 2; m++) {
    const int q = wave * 32 + m * 16 + l15;
#pragma unroll
    for (int kk = 0; kk < 4; kk++) {
      const int u = (kk * 4 + g) ^ (q & 7);
      af[m][kk] = *(const bf16x8*)(Qs + q * 128 + u * 8);
    }
  }
  __syncthreads();  // Qs dead; safe to overlay P

  f32x4 sacc[2][4] = {};
#pragma unroll
  for (int n = 0; n < 4; n++) {
    if (n < ntk) {
      const bf16* kr = kbase + (n * 16 + l15) * 128 + g * 8;
      bf16x8 b0 = *(const bf16x8*)(kr);
      bf16x8 b1 = *(const bf16x8*)(kr + 32);
      bf16x8 b2 = *(const bf16x8*)(kr + 64);
      bf16x8 b3 = *(const bf16x8*)(kr + 96);
      __builtin_amdgcn_s_setprio(1);
      sacc[0][n] = mfma16(af[0][0], b0, sacc[0][n]);
      sacc[1][n] = mfma16(af[1][0], b0, sacc[1][n]);
      sacc[0][n] = mfma16(af[0][1], b1, sacc[0][n]);
      sacc[1][n] = mfma16(af[1][1], b1, sacc[1][n]);
      sacc[0][n] = mfma16(af[0][2], b2, sacc[0][n]);
      sacc[1][n] = mfma16(af[1][2], b2, sacc[1][n]);
      sacc[0][n] = mfma16(af[0][3], b3, sacc[0][n]);
      sacc[1][n] = mfma16(af[1][3], b3, sacc[1][n]);
      __builtin_amdgcn_s_setprio(0);
    }
  }

  const float sink = expf(sink_logits[hh]);
  const float scale = 0.088388347648318447f;  // 1/sqrt(128)
  bf16* P = Qs;
#pragma unroll
  for (int m = 0; m < 2; m++) {
    float pv[4][4];
    float rs[4] = {0.f, 0.f, 0.f, 0.f};
#pragma unroll
    for (int n = 0; n < 4; n++) {
      int key = n * 16 + l15;
#pragma unroll
      for (int j = 0; j < 4; j++) {
        float p = (key < nk) ? expf(sacc[m][n][j] * scale) : 0.f;
        pv[n][j] = p;
        rs[j] += p;
      }
    }
#pragma unroll
    for (int j = 0; j < 4; j++) {
      float v = rs[j];
      v += __shfl_xor(v, 1); v += __shfl_xor(v, 2);
      v += __shfl_xor(v, 4); v += __shfl_xor(v, 8);
      rs[j] = 1.0f / (v + sink);
    }
    const int row0 = wave * 32 + m * 16 + (g << 2);
#pragma unroll
    for (int n = 0; n < 4; n++)
#pragma unroll
      for (int j = 0; j < 4; j++) {
        int q = row0 + j;
        int k = n * 16 + l15;
        P[q * 64 + ((((k >> 3) ^ (q & 7)) << 3) | (k & 7))] =
            __float2bfloat16(pv[n][j] * rs[j]);
      }
  }
  // no barrier: PV reads only this wave's own P rows

  f32x4 oacc[2][8] = {};
#pragma unroll
  for (int kk = 0; kk < 2; kk++) {
    if (kk < nkk) {
      bf16x8 pa[2];
#pragma unroll
      for (int m = 0; m < 2; m++) {
        const int q = wave * 32 + m * 16 + l15;
        const int u = (kk * 4 + g) ^ (q & 7);
        pa[m] = *(const bf16x8*)(P + q * 64 + u * 8);
      }
#pragma unroll
      for (int n = 0; n < 8; n++) {
        bf16x8 vb = *(const bf16x8*)(vbase + (n * 16 + l15) * 64 + kk * 32 + g * 8);
        __builtin_amdgcn_s_setprio(1);
        oacc[0][n] = mfma16(pa[0], vb, oacc[0][n]);
        oacc[1][n] = mfma16(pa[1], vb, oacc[1][n]);
        __builtin_amdgcn_s_setprio(0);
      }
    }
  }

  bf16* ob = out + t0 * 2048 + hh * 128;
  const int r4 = g << 2;
#pragma unroll
  for (int m = 0; m < 2; m++)
#pragma unroll
    for (int n = 0; n < 8; n++)
#pragma unroll
      for (int j = 0; j < 4; j++)
        ob[(size_t)(wave * 32 + m * 16 + r4 + j) * 2048 + n * 16 + l15] =
            __float2bfloat16(oacc[m][n][j]);
}

extern "C" void kernel_launch(void* const* d_in, const int* in_sizes, int n_in,
                              void* d_out, int out_size, void* d_ws, size_t ws_size,
                              hipStream_t stream) {
  const float* x      = (const float*)d_in[0];
  const float* w_kv   = (const float*)d_in[1];
  const float* w_z    = (const float*)d_in[2];
  const float* b_comp = (const float*)d_in[3];
  const float* w_dq   = (const float*)d_in[4];
  const float* w_uq   = (const float*)d_in[5];
  const float* o_down = (const float*)d_in[6];
  const float* o_up   = (const float*)d_in[7];
  const float* kv_g   = (const float*)d_in[8];
  const float* kv_b   = (const float*)d_in[9];
  const float* q_g    = (const float*)d_in[10];
  const float* q_b    = (const float*)d_in[11];
  const float* sinkl  = (const float*)d_in[12];
  char* ws = (char*)d_ws;
  bf16*   WCZQ  = (bf16*)(ws + OFF_WCZQ);
  bf16*   WUQ   = (bf16*)(ws + OFF_WUQ);
  bf16*   DOWNB = (bf16*)(ws + OFF_DOWNB);
  bf16*   WUP   = (bf16*)(ws + OFF_WUP);
  bf16*   W2T   = (bf16*)(ws + OFF_W2T);
  bf16*   KC    = (bf16*)(ws + OFF_KC);
  bf16*   VT    = (bf16*)(ws + OFF_VT);
  float2* ROPE  = (float2*)(ws + OFF_ROPE);
  bf16*   XB    = (bf16*)(ws + OFF_XB);
  bf16*   CZQ   = (bf16*)(ws + OFF_CZQ);
  bf16*   QF    = (bf16*)(ws + OFF_QF);
  bf16*   ATT   = (bf16*)(ws + OFF_XB);
  float*  OUT   = (float*)d_out;

  // all weight prep + converts + rope table in one launch
  prep_k<<<24576, 256, 0, stream>>>(w_kv, w_z, w_dq, w_uq, o_up, o_down, x,
                                    WCZQ, WUQ, WUP, DOWNB, XB, ROPE);
  // czq GEMM (16384x768) + W2T group GEMMs, one full-machine launch
  czq_w2t_k<<<256, 1024, 0, stream>>>(XB, WCZQ, CZQ, WUP, DOWNB, W2T);
  // compression + kv LN (writes K row-major and V^T)
  compress_k<<<128, 512, 0, stream>>>(CZQ, 768, b_comp, kv_g, kv_b, KC, VT);
  // q = q_mid @ w_uq   (16384 x 2048, K=512)
  gemm8p<1><<<512, 1024, 0, stream>>>(CZQ + 256, 768, WUQ, 512, QF, DM, 512, 8);
  // attention (fused q-LN + rope)
  attn_k<<<dim3(64, 16, 2), 256, 0, stream>>>(QF, KC, VT, sinkl, q_g, q_b, ROPE, ATT);
  // final: OUT = ATT @ W2T^T  (16384 x 2048, K=2048)
  gemm8p<0><<<512, 1024, 0, stream>>>(ATT, DM, W2T, DM, OUT, DM, DM, 8);
}